// Round 1
// baseline (1191.802 us; speedup 1.0000x reference)
//
#include <hip/hip_runtime.h>
#include <hip/hip_bf16.h>
#include <math.h>

#define B_   8
#define S_   2048
#define IN_  512
#define OUT_ 256
#define G_   8

// ws layout:
//  big path (ws >= 39 MiB):
//   [0,16MiB) y  [16,32MiB) Xb  [32,32.5) Wb  [33,39) PTK (un-aliased)
//  mid path (32.5 <= ws < 39 MiB): PTK aliases Xb at 16 MiB, written after gemm
//  fallback (ws < 32.5 MiB): fp32 gemm, y [0,16), PTK [16,22)
// PTK layout (R8): per j, 6 float4-quads x 256 i:
//   quad0 p[0..3] | quad1 p[4..7] | quad2 iT[0..3] | quad3 iT[4..7] | quad4 2cos(2pi iT)[0..3] | quad5 [4..7]

typedef float  f32x2  __attribute__((ext_vector_type(2)));
typedef float  f32x4  __attribute__((ext_vector_type(4)));
typedef short  s16x8  __attribute__((ext_vector_type(8)));
typedef __bf16 bf16x8 __attribute__((ext_vector_type(8)));
typedef unsigned short u16x8 __attribute__((ext_vector_type(8)));

__device__ __forceinline__ float cos2pi(float f) {
#if __has_builtin(__builtin_amdgcn_cosf)
    return __builtin_amdgcn_cosf(f);   // v_cos_f32: revolutions (verified R1-R7)
#else
    return __cosf(6.28318530717958647692f * f);
#endif
}

__device__ __forceinline__ float fractf_(float f) {
#if __has_builtin(__builtin_amdgcn_fractf)
    return __builtin_amdgcn_fractf(f);
#else
    return f - floorf(f);
#endif
}

__device__ __forceinline__ unsigned short f2bf(float f) {
    unsigned u = __builtin_bit_cast(unsigned, f);
    u += 0x7fffu + ((u >> 16) & 1u);   // RNE; inputs finite
    return (unsigned short)(u >> 16);
}

// hardware f32 atomic add when available; fallback atomicAdd
template <typename T>
__device__ __forceinline__ auto atomF_(T* p, T v, int) -> decltype(unsafeAtomicAdd(p, v)) {
    return unsafeAtomicAdd(p, v);
}
template <typename T>
__device__ __forceinline__ T atomF_(T* p, T v, long) {
    return atomicAdd(p, v);
}
__device__ __forceinline__ void atomAddF(float* p, float v) { atomF_(p, v, 0); }

// --- MFMA wrapper: tolerate either V8s(short) or V8y(__bf16) builtin signature ---
template <typename T>
__device__ __forceinline__ auto mfma_bf16_(T a, T b, f32x4 c, int)
    -> decltype(__builtin_amdgcn_mfma_f32_16x16x32_bf16(a, b, c, 0, 0, 0)) {
    return __builtin_amdgcn_mfma_f32_16x16x32_bf16(a, b, c, 0, 0, 0);
}
template <typename T>
__device__ __forceinline__ auto mfma_bf16_(T a, T b, f32x4 c, long)
    -> decltype(__builtin_amdgcn_mfma_f32_16x16x32_bf16(__builtin_bit_cast(bf16x8, a),
                                                        __builtin_bit_cast(bf16x8, b), c, 0, 0, 0)) {
    return __builtin_amdgcn_mfma_f32_16x16x32_bf16(__builtin_bit_cast(bf16x8, a),
                                                   __builtin_bit_cast(bf16x8, b), c, 0, 0, 0);
}
__device__ __forceinline__ f32x4 mfma_bf16(s16x8 a, s16x8 b, f32x4 c) {
    return mfma_bf16_(a, b, c, 0);
}

__device__ __forceinline__ void gld16(const void* g, void* l) {
    __builtin_amdgcn_global_load_lds((const __attribute__((address_space(1))) unsigned int*)g,
                                     (__attribute__((address_space(3))) unsigned int*)l,
                                     16, 0, 0);
}

__device__ __forceinline__ f32x2 lo2(float4 v) { f32x2 r; r.x = v.x; r.y = v.y; return r; }
__device__ __forceinline__ f32x2 hi2(float4 v) { f32x2 r; r.x = v.z; r.y = v.w; return r; }

// ---------------- device helper: prep one PTK record (pair-friendly layout) ----------------
__device__ __forceinline__ void prep_one(const float* __restrict__ P,
                                         const float* __restrict__ periods,
                                         float4* __restrict__ PTK, int tid) {
    const int j = tid >> 8, i = tid & 255;
    float p[8], iT[8], k2[8];
#pragma unroll
    for (int g = 0; g < 8; ++g) {
        const int idx = (i * 256 + j) * 8 + g;
        p[g]  = P[idx];
        iT[g] = 1.0f / periods[idx];
        k2[g] = 2.0f * cos2pi(iT[g]);
    }
    float4* base = PTK + (size_t)(j * 6) * 256 + i;
    base[0]    = make_float4(p[0],  p[1],  p[2],  p[3]);
    base[256]  = make_float4(p[4],  p[5],  p[6],  p[7]);
    base[512]  = make_float4(iT[0], iT[1], iT[2], iT[3]);
    base[768]  = make_float4(iT[4], iT[5], iT[6], iT[7]);
    base[1024] = make_float4(k2[0], k2[1], k2[2], k2[3]);
    base[1280] = make_float4(k2[4], k2[5], k2[6], k2[7]);
}

// ---------------- fused convert (x, W) + PTK prep: one launch (big path) ----------------
__global__ __launch_bounds__(256) void cvt_prep(const float* __restrict__ x,
                                                const float* __restrict__ M,
                                                const float* __restrict__ Wres,
                                                const float* __restrict__ P,
                                                const float* __restrict__ periods,
                                                unsigned short* __restrict__ Xb,
                                                unsigned short* __restrict__ Wb,
                                                float4* __restrict__ PTK) {
    const int bid = blockIdx.x;
    if (bid >= 4224) {                       // PTK prep: 256 blocks
        prep_one(P, periods, PTK, (bid - 4224) * 256 + threadIdx.x);
        return;
    }
    const float* src;
    unsigned short* dst;
    if (bid < 4096) {
        const int idx = bid * 256 + threadIdx.x;
        src = x + (size_t)idx * 8;
        dst = Xb + (size_t)idx * 8;
    } else {
        const int idx = (bid - 4096) * 256 + threadIdx.x;
        const int row = idx >> 6;
        const int col = (idx & 63) * 8;
        src = (row < 256) ? (M + (size_t)row * 512 + col)
                          : (Wres + (size_t)(row - 256) * 512 + col);
        dst = Wb + (size_t)row * 512 + col;
    }
    const float4 v0 = *(const float4*)(src);
    const float4 v1 = *(const float4*)(src + 4);
    u16x8 o;
    o[0] = f2bf(v0.x); o[1] = f2bf(v0.y); o[2] = f2bf(v0.z); o[3] = f2bf(v0.w);
    o[4] = f2bf(v1.x); o[5] = f2bf(v1.y); o[6] = f2bf(v1.z); o[7] = f2bf(v1.w);
    *(u16x8*)dst = o;
}

// standalone versions for the aliased / fallback paths
__global__ __launch_bounds__(256) void cvt_xw(const float* __restrict__ x,
                                              const float* __restrict__ M,
                                              const float* __restrict__ Wres,
                                              unsigned short* __restrict__ Xb,
                                              unsigned short* __restrict__ Wb) {
    const int bid = blockIdx.x;
    const float* src;
    unsigned short* dst;
    if (bid < 4096) {
        const int idx = bid * 256 + threadIdx.x;
        src = x + (size_t)idx * 8;
        dst = Xb + (size_t)idx * 8;
    } else {
        const int idx = (bid - 4096) * 256 + threadIdx.x;
        const int row = idx >> 6;
        const int col = (idx & 63) * 8;
        src = (row < 256) ? (M + (size_t)row * 512 + col)
                          : (Wres + (size_t)(row - 256) * 512 + col);
        dst = Wb + (size_t)row * 512 + col;
    }
    const float4 v0 = *(const float4*)(src);
    const float4 v1 = *(const float4*)(src + 4);
    u16x8 o;
    o[0] = f2bf(v0.x); o[1] = f2bf(v0.y); o[2] = f2bf(v0.z); o[3] = f2bf(v0.w);
    o[4] = f2bf(v1.x); o[5] = f2bf(v1.y); o[6] = f2bf(v1.z); o[7] = f2bf(v1.w);
    *(u16x8*)dst = o;
}

__global__ __launch_bounds__(256) void prep_ptk(const float* __restrict__ P,
                                                const float* __restrict__ periods,
                                                float4* __restrict__ PTK) {
    prep_one(P, periods, PTK, blockIdx.x * 256 + threadIdx.x);
}

// ---------------- bf16 MFMA GEMM: C[16384,512] = Xb * Wb^T (unchanged, proven R5-R7) ----------------
__global__ __launch_bounds__(256) void gemm_mfma(const unsigned short* __restrict__ Xb,
                                                 const unsigned short* __restrict__ Wb,
                                                 float* __restrict__ y,
                                                 float* __restrict__ out) {
    __shared__ __align__(16) unsigned short At[64 * 64];    // 8 KB
    __shared__ __align__(16) unsigned short Bt[128 * 64];   // 16 KB
    const int t    = threadIdx.x;
    const int col0 = blockIdx.x * 128;
    const int row0 = blockIdx.y * 64;

    const unsigned short* ga[2]; int la[2];
    const unsigned short* gb[4]; int lb[4];
#pragma unroll
    for (int cc = 0; cc < 2; ++cc) {
        const int L = cc * 256 + t;
        const int r = L >> 3;
        const int c = (L & 7) ^ (r & 7);
        ga[cc] = Xb + (size_t)(row0 + r) * 512 + c * 8;
        la[cc] = L * 8;
    }
#pragma unroll
    for (int cc = 0; cc < 4; ++cc) {
        const int L = cc * 256 + t;
        const int r = L >> 3;
        const int c = (L & 7) ^ (r & 7);
        gb[cc] = Wb + (size_t)(col0 + r) * 512 + c * 8;
        lb[cc] = L * 8;
    }

    const int lane = t & 63;
    const int wave = t >> 6;
    const int wn   = wave * 32;
    const int quad = lane >> 4;
    const int l16  = lane & 15;

    f32x4 acc[4][2];
#pragma unroll
    for (int mi = 0; mi < 4; ++mi)
#pragma unroll
        for (int ni = 0; ni < 2; ++ni) acc[mi][ni] = {0.0f, 0.0f, 0.0f, 0.0f};

    for (int k0 = 0; k0 < 512; k0 += 64) {
        __syncthreads();
#pragma unroll
        for (int cc = 0; cc < 2; ++cc) gld16(ga[cc] + k0, At + la[cc]);
#pragma unroll
        for (int cc = 0; cc < 4; ++cc) gld16(gb[cc] + k0, Bt + lb[cc]);
        __syncthreads();
#pragma unroll
        for (int ks = 0; ks < 2; ++ks) {
            const int cc = (ks * 4 + quad) ^ (l16 & 7);
            s16x8 af[4], bf[2];
#pragma unroll
            for (int mi = 0; mi < 4; ++mi) {
                const int ra = mi * 16 + l16;
                af[mi] = *(const s16x8*)(At + (ra * 8 + cc) * 8);
            }
#pragma unroll
            for (int ni = 0; ni < 2; ++ni) {
                const int rb = wn + ni * 16 + l16;
                bf[ni] = *(const s16x8*)(Bt + (rb * 8 + cc) * 8);
            }
#pragma unroll
            for (int mi = 0; mi < 4; ++mi)
#pragma unroll
                for (int ni = 0; ni < 2; ++ni)
                    acc[mi][ni] = mfma_bf16(af[mi], bf[ni], acc[mi][ni]);
        }
    }

    float* dst   = (col0 < 256) ? y : out;
    const int cb = (col0 & 255) + wn;
#pragma unroll
    for (int mi = 0; mi < 4; ++mi) {
        const int rbase = row0 + mi * 16 + quad * 4;
#pragma unroll
        for (int ni = 0; ni < 2; ++ni) {
            const int col = cb + ni * 16 + l16;
#pragma unroll
            for (int rg = 0; rg < 4; ++rg)
                dst[(size_t)(rbase + rg) * 256 + col] = acc[mi][ni][rg];
        }
    }
}

// ---------------- fallback fp32 GEMM (proven) ----------------
__global__ __launch_bounds__(256) void gemm_kernel(const float* __restrict__ x,
                                                   const float* __restrict__ M,
                                                   const float* __restrict__ Wres,
                                                   float* __restrict__ y,
                                                   float* __restrict__ out) {
    __shared__ float As[8][132];
    __shared__ float Bs[8][132];
    const int ct = blockIdx.x;
    const int rt = blockIdx.y;
    const int t  = threadIdx.x;
    const int row0 = rt * 128;
    const float* W = (ct < 2) ? M : Wres;
    const int wcol0 = (ct & 1) * 128;
    float acc[8][8];
#pragma unroll
    for (int r = 0; r < 8; ++r)
#pragma unroll
        for (int c = 0; c < 8; ++c) acc[r][c] = 0.0f;
    const int lr = t >> 1;
    const int lk = (t & 1) << 2;
    for (int k0 = 0; k0 < 512; k0 += 8) {
        float4 av = *(const float4*)(x + (size_t)(row0 + lr) * 512 + k0 + lk);
        float4 bv = *(const float4*)(W + (size_t)(wcol0 + lr) * 512 + k0 + lk);
        __syncthreads();
        As[lk + 0][lr] = av.x; As[lk + 1][lr] = av.y; As[lk + 2][lr] = av.z; As[lk + 3][lr] = av.w;
        Bs[lk + 0][lr] = bv.x; Bs[lk + 1][lr] = bv.y; Bs[lk + 2][lr] = bv.z; Bs[lk + 3][lr] = bv.w;
        __syncthreads();
        const int tx = t & 15, ty = t >> 4;
#pragma unroll
        for (int kk = 0; kk < 8; ++kk) {
            const float4 a0 = *(const float4*)&As[kk][ty * 8];
            const float4 a1 = *(const float4*)&As[kk][ty * 8 + 4];
            const float4 b0 = *(const float4*)&Bs[kk][tx * 8];
            const float4 b1 = *(const float4*)&Bs[kk][tx * 8 + 4];
            const float ar[8] = {a0.x, a0.y, a0.z, a0.w, a1.x, a1.y, a1.z, a1.w};
            const float br[8] = {b0.x, b0.y, b0.z, b0.w, b1.x, b1.y, b1.z, b1.w};
#pragma unroll
            for (int r = 0; r < 8; ++r)
#pragma unroll
                for (int c = 0; c < 8; ++c) acc[r][c] = fmaf(ar[r], br[c], acc[r][c]);
        }
    }
    const int tx = t & 15, ty = t >> 4;
    float* dst = (ct < 2) ? y : out;
    const int cbase = (ct & 1) * 128 + tx * 8;
#pragma unroll
    for (int r = 0; r < 8; ++r) {
        float4 v0 = {acc[r][0], acc[r][1], acc[r][2], acc[r][3]};
        float4 v1 = {acc[r][4], acc[r][5], acc[r][6], acc[r][7]};
        float* p = dst + (size_t)(row0 + ty * 8 + r) * 256 + cbase;
        *(float4*)(p)     = v0;
        *(float4*)(p + 4) = v1;
    }
}

// ---------------- LayerNorm (in-place; restored from R6 — fusion measured -8 net in R7) ----------------
__global__ __launch_bounds__(256) void ln_kernel(float* __restrict__ y,
                                                 const float* __restrict__ scale,
                                                 const float* __restrict__ bias) {
    const int t    = threadIdx.x;
    const int row  = blockIdx.x * 4 + (t >> 6);
    const int lane = t & 63;
    float* p = y + (size_t)row * 256 + lane * 4;
    float4 v = *(float4*)p;
    float s  = v.x + v.y + v.z + v.w;
    float ss = v.x * v.x + v.y * v.y + v.z * v.z + v.w * v.w;
#pragma unroll
    for (int off = 32; off > 0; off >>= 1) {
        s  += __shfl_xor(s, off);
        ss += __shfl_xor(ss, off);
    }
    const float mu  = s * (1.0f / 256.0f);
    const float var = ss * (1.0f / 256.0f) - mu * mu;
    const float rs  = rsqrtf(var + 1e-5f);
    float4 sc = *(const float4*)(scale + lane * 4);
    float4 bi = *(const float4*)(bias + lane * 4);
    float4 o;
    o.x = (v.x - mu) * rs * sc.x + bi.x;
    o.y = (v.y - mu) * rs * sc.y + bi.y;
    o.z = (v.z - mu) * rs * sc.z + bi.z;
    o.w = (v.w - mu) * rs * sc.w + bi.w;
    *(float4*)p = o;
}

// ---------------- fused A-gen + contraction: R8 structure, occupancy-doubled ----------------
// R9: j-quarter blocks. grid 2048 = 2 ih x 256 stile x 4 jQ; LDS 16KB -> 8 blocks/CU
// (32 waves/CU, was 4 blocks/16 waves). VGPR=64 fits 8 waves/SIMD; launch_bounds(256,8).
// Each block: 8 s x 128 i (ih) x 64 j (jQ); threads = 128 i x 2 jq (32 j each).
// Chebyshev recurrences packed over g-pairs (f32x2 -> v_pk_fma_f32); b-accumulation
// packed over b-pairs. cos/fract remain scalar (transcendental pipe).
__global__ __launch_bounds__(256, 8) void cosnk_pk(const float4* __restrict__ PTK,
                                                   const float* __restrict__ xt,
                                                   float* __restrict__ out) {
    __shared__ float xs[64 * 64];    // [j_local][slot=s*8+b], 16 KB; reused for reduce
    const int t  = threadIdx.x;
    const int bx = blockIdx.x;
    const int ih = (bx >> 2) & 1;                  // XCD-pinned i-half (bx%8<4 -> 0)
    const int rid = ((bx >> 3) << 2) | (bx & 3);   // 0..1023
    const int stile = rid >> 2;                    // 0..255
    const int jq4 = rid & 3;                       // j-quarter
    const int s0 = stile * 8;
    const int jbase = jq4 * 64;

    {   // stage x_t[b][s0+st][jbase..+64] -> xs[j_local][slot]
        const int slot = t >> 2;        // 0..63 = st*8+b
        const int st   = slot >> 3;
        const int b    = slot & 7;
        const int jg   = t & 3;         // 16-j group
        const float* src = xt + (size_t)(b * S_ + s0 + st) * 256 + jbase + jg * 16;
#pragma unroll
        for (int q = 0; q < 4; ++q) {
            float4 v = *(const float4*)(src + 4 * q);
            const int jl = jg * 16 + 4 * q;
            xs[(jl + 0) * 64 + slot] = v.x;
            xs[(jl + 1) * 64 + slot] = v.y;
            xs[(jl + 2) * 64 + slot] = v.z;
            xs[(jl + 3) * 64 + slot] = v.w;
        }
    }
    __syncthreads();

    const int i   = ih * 128 + (t & 127);
    const int jq  = t >> 7;             // 0 or 1: 32-j eighth
    const int jl0 = jq * 32;
    const float sv0 = (float)s0;
    f32x2 sv0v; sv0v.x = sv0; sv0v.y = sv0;

    f32x2 accP[8][4];                   // [s][b-pair]
#pragma unroll
    for (int s = 0; s < 8; ++s)
#pragma unroll
        for (int q = 0; q < 4; ++q) { accP[s][q].x = 0.0f; accP[s][q].y = 0.0f; }

    const float4* ptk = PTK + (size_t)(jbase + jl0) * 1536 + i;
    float4 qp0 = ptk[0],    qp1 = ptk[256];   // p pairs
    float4 qt0 = ptk[512],  qt1 = ptk[768];   // iT pairs
    float4 qk0 = ptk[1024], qk1 = ptk[1280];  // 2cos(2pi iT) pairs

#define CHEBP(p2_, t2_, k2_)                                \
    do {                                                    \
        f32x2 f0 = sv0v * (t2_);                            \
        f0.x = fractf_(f0.x); f0.y = fractf_(f0.y);         \
        f32x2 c0; c0.x = cos2pi(f0.x); c0.y = cos2pi(f0.y); \
        f32x2 f1 = f0 + (t2_);                              \
        f1.x = fractf_(f1.x); f1.y = fractf_(f1.y);         \
        f32x2 c1; c1.x = cos2pi(f1.x); c1.y = cos2pi(f1.y); \
        f32x2 c2 = (k2_) * c1 - c0;                         \
        f32x2 c3 = (k2_) * c2 - c1;                         \
        f32x2 c4 = (k2_) * c3 - c2;                         \
        f32x2 c5 = (k2_) * c4 - c3;                         \
        f32x2 c6 = (k2_) * c5 - c4;                         \
        f32x2 c7 = (k2_) * c6 - c5;                         \
        A0 += (p2_) * c0; A1 += (p2_) * c1;                 \
        A2 += (p2_) * c2; A3 += (p2_) * c3;                 \
        A4 += (p2_) * c4; A5 += (p2_) * c5;                 \
        A6 += (p2_) * c6; A7 += (p2_) * c7;                 \
    } while (0)

    for (int jj = 0; jj < 32; ++jj) {
        const float4* pn = ptk + ((jj < 31) ? 1536 : 0);   // next-j prefetch
        const float4 n0 = pn[0],   n1 = pn[256],  n2 = pn[512];
        const float4 n3 = pn[768], n4 = pn[1024], n5 = pn[1280];

        f32x2 A0 = {0.f, 0.f}, A1 = {0.f, 0.f}, A2 = {0.f, 0.f}, A3 = {0.f, 0.f};
        f32x2 A4 = {0.f, 0.f}, A5 = {0.f, 0.f}, A6 = {0.f, 0.f}, A7 = {0.f, 0.f};
        CHEBP(lo2(qp0), lo2(qt0), lo2(qk0));   // g0,g1
        CHEBP(hi2(qp0), hi2(qt0), hi2(qk0));   // g2,g3
        CHEBP(lo2(qp1), lo2(qt1), lo2(qk1));   // g4,g5
        CHEBP(hi2(qp1), hi2(qt1), hi2(qk1));   // g6,g7

        const float as_[8] = {A0.x + A0.y, A1.x + A1.y, A2.x + A2.y, A3.x + A3.y,
                              A4.x + A4.y, A5.x + A5.y, A6.x + A6.y, A7.x + A7.y};

        const float* xrow = &xs[(jl0 + jj) * 64];   // wave-uniform -> LDS broadcast
#pragma unroll
        for (int s = 0; s < 8; ++s) {
            const float4 xa = *(const float4*)(xrow + s * 8);
            const float4 xb = *(const float4*)(xrow + s * 8 + 4);
            f32x2 av; av.x = as_[s]; av.y = as_[s];
            accP[s][0] += av * lo2(xa);
            accP[s][1] += av * hi2(xa);
            accP[s][2] += av * lo2(xb);
            accP[s][3] += av * hi2(xb);
        }
        qp0 = n0; qp1 = n1; qt0 = n2; qt1 = n3; qk0 = n4; qk1 = n5;
        ptk = pn;
    }
#undef CHEBP

    // intra-block jq-reduce (two 16KB rounds: xs holds 32 slots x 128 i), then
    // device-scope atomic add (4 blocks per output element)
    const int tl = t & 127;
    __syncthreads();
#pragma unroll
    for (int half = 0; half < 2; ++half) {
        if (jq) {
#pragma unroll
            for (int s2 = 0; s2 < 32; ++s2) {
                const int slot = half * 32 + s2;
                const int st = slot >> 3, b = slot & 7;
                xs[s2 * 128 + tl] = accP[st][b >> 1][b & 1];
            }
        }
        __syncthreads();
        if (!jq) {
#pragma unroll
            for (int s2 = 0; s2 < 32; ++s2) {
                const int slot = half * 32 + s2;
                const int st = slot >> 3, b = slot & 7;
                const float v = accP[st][b >> 1][b & 1] + xs[s2 * 128 + tl];
                atomAddF(&out[(size_t)(b * S_ + s0 + st) * 256 + i], v);
            }
        }
        if (half == 0) __syncthreads();
    }
}

extern "C" void kernel_launch(void* const* d_in, const int* in_sizes, int n_in,
                              void* d_out, int out_size, void* d_ws, size_t ws_size,
                              hipStream_t stream) {
    const float* x        = (const float*)d_in[0];
    const float* M        = (const float*)d_in[1];
    const float* P        = (const float*)d_in[2];
    const float* Wres     = (const float*)d_in[3];
    const float* ln_scale = (const float*)d_in[4];
    const float* ln_bias  = (const float*)d_in[5];
    const float* periods  = (const float*)d_in[6];

    float* out = (float*)d_out;
    char*  wsb = (char*)d_ws;
    const size_t MB = 1024 * 1024;
    float* y = (float*)wsb;                                     // 16 MiB
    unsigned short* Xb = (unsigned short*)(wsb + 16 * MB);      // 16 MiB
    unsigned short* Wb = (unsigned short*)(wsb + 32 * MB);      // 0.5 MiB

    const bool big  = (ws_size >= 39 * MB);        // un-aliased PTK at 33 MiB
    const bool mfma = (ws_size >= (size_t)34078720);

    float4* PTK;
    if (big) {
        PTK = (float4*)(wsb + 33 * MB);
        cvt_prep<<<4480, 256, 0, stream>>>(x, M, Wres, P, periods, Xb, Wb, PTK);
        dim3 ggrid(4, 256);
        gemm_mfma<<<ggrid, 256, 0, stream>>>(Xb, Wb, y, out);
    } else if (mfma) {
        PTK = (float4*)(wsb + 16 * MB);            // aliases Xb; written after gemm
        cvt_xw<<<4224, 256, 0, stream>>>(x, M, Wres, Xb, Wb);
        dim3 ggrid(4, 256);
        gemm_mfma<<<ggrid, 256, 0, stream>>>(Xb, Wb, y, out);
        prep_ptk<<<256, 256, 0, stream>>>(P, periods, PTK);
    } else {
        PTK = (float4*)(wsb + 16 * MB);
        dim3 ggrid(4, 128);
        gemm_kernel<<<ggrid, 256, 0, stream>>>(x, M, Wres, y, out);
        prep_ptk<<<256, 256, 0, stream>>>(P, periods, PTK);
    }

    ln_kernel<<<4096, 256, 0, stream>>>(y, ln_scale, ln_bias);

    cosnk_pk<<<2048, 256, 0, stream>>>(PTK, y, out);
}

// Round 3
// 306.544 us; speedup vs baseline: 3.8879x; 3.8879x over previous
//
#include <hip/hip_runtime.h>
#include <hip/hip_bf16.h>
#include <math.h>

#define B_   8
#define S_   2048
#define IN_  512
#define OUT_ 256
#define G_   8

// ws layout:
//  big path (ws >= 39 MiB):
//   [0,16MiB) y  [16,32MiB) Xb (reused as xt2 after gemm)  [32,32.5) Wb  [33,39) PTK
//  mid path (32.5 <= ws < 39 MiB): PTK aliases Xb at 16 MiB, written after gemm
//  fallback (ws < 32.5 MiB): fp32 gemm, y [0,16), PTK [16,22)
// PTK layout (R8): per j, 6 float4-quads x 256 i:
//   quad0 p[0..3] | quad1 p[4..7] | quad2 iT[0..3] | quad3 iT[4..7] | quad4 2cos(2pi iT)[0..3] | quad5 [4..7]
// R9 LESSON: true cosnk register demand ~128 (64 arch + ~64 acc, unified file).
// __launch_bounds__ min-waves > 4 caps below demand -> accP spills to scratch ->
// 1.8GB/3.6GB HBM traffic, 9x slowdown. Keep (256,4); occupancy lever is closed.
// R10: x broadcast moved from LDS staging (16 ds_read_b128/jj + barrier) to the
// SCALAR pipe: ln_t writes LN output transposed [stile][j][st][b]; cosnk_sx reads
// one 256B wave-uniform chunk per jj via readfirstlane-hoisted pointer -> s_load.
// R11 = R10 resubmitted verbatim (R10 bench was GPUAcquisitionTimeout; no data).

typedef float  f32x2  __attribute__((ext_vector_type(2)));
typedef float  f32x4  __attribute__((ext_vector_type(4)));
typedef short  s16x8  __attribute__((ext_vector_type(8)));
typedef __bf16 bf16x8 __attribute__((ext_vector_type(8)));
typedef unsigned short u16x8 __attribute__((ext_vector_type(8)));

__device__ __forceinline__ float cos2pi(float f) {
#if __has_builtin(__builtin_amdgcn_cosf)
    return __builtin_amdgcn_cosf(f);   // v_cos_f32: revolutions (verified R1-R7)
#else
    return __cosf(6.28318530717958647692f * f);
#endif
}

__device__ __forceinline__ float fractf_(float f) {
#if __has_builtin(__builtin_amdgcn_fractf)
    return __builtin_amdgcn_fractf(f);
#else
    return f - floorf(f);
#endif
}

__device__ __forceinline__ unsigned short f2bf(float f) {
    unsigned u = __builtin_bit_cast(unsigned, f);
    u += 0x7fffu + ((u >> 16) & 1u);   // RNE; inputs finite
    return (unsigned short)(u >> 16);
}

// hardware f32 atomic add when available; fallback atomicAdd
template <typename T>
__device__ __forceinline__ auto atomF_(T* p, T v, int) -> decltype(unsafeAtomicAdd(p, v)) {
    return unsafeAtomicAdd(p, v);
}
template <typename T>
__device__ __forceinline__ T atomF_(T* p, T v, long) {
    return atomicAdd(p, v);
}
__device__ __forceinline__ void atomAddF(float* p, float v) { atomF_(p, v, 0); }

// --- MFMA wrapper: tolerate either V8s(short) or V8y(__bf16) builtin signature ---
template <typename T>
__device__ __forceinline__ auto mfma_bf16_(T a, T b, f32x4 c, int)
    -> decltype(__builtin_amdgcn_mfma_f32_16x16x32_bf16(a, b, c, 0, 0, 0)) {
    return __builtin_amdgcn_mfma_f32_16x16x32_bf16(a, b, c, 0, 0, 0);
}
template <typename T>
__device__ __forceinline__ auto mfma_bf16_(T a, T b, f32x4 c, long)
    -> decltype(__builtin_amdgcn_mfma_f32_16x16x32_bf16(__builtin_bit_cast(bf16x8, a),
                                                        __builtin_bit_cast(bf16x8, b), c, 0, 0, 0)) {
    return __builtin_amdgcn_mfma_f32_16x16x32_bf16(__builtin_bit_cast(bf16x8, a),
                                                   __builtin_bit_cast(bf16x8, b), c, 0, 0, 0);
}
__device__ __forceinline__ f32x4 mfma_bf16(s16x8 a, s16x8 b, f32x4 c) {
    return mfma_bf16_(a, b, c, 0);
}

__device__ __forceinline__ void gld16(const void* g, void* l) {
    __builtin_amdgcn_global_load_lds((const __attribute__((address_space(1))) unsigned int*)g,
                                     (__attribute__((address_space(3))) unsigned int*)l,
                                     16, 0, 0);
}

__device__ __forceinline__ f32x2 lo2(float4 v) { f32x2 r; r.x = v.x; r.y = v.y; return r; }
__device__ __forceinline__ f32x2 hi2(float4 v) { f32x2 r; r.x = v.z; r.y = v.w; return r; }

// ---------------- device helper: prep one PTK record (pair-friendly layout) ----------------
__device__ __forceinline__ void prep_one(const float* __restrict__ P,
                                         const float* __restrict__ periods,
                                         float4* __restrict__ PTK, int tid) {
    const int j = tid >> 8, i = tid & 255;
    float p[8], iT[8], k2[8];
#pragma unroll
    for (int g = 0; g < 8; ++g) {
        const int idx = (i * 256 + j) * 8 + g;
        p[g]  = P[idx];
        iT[g] = 1.0f / periods[idx];
        k2[g] = 2.0f * cos2pi(iT[g]);
    }
    float4* base = PTK + (size_t)(j * 6) * 256 + i;
    base[0]    = make_float4(p[0],  p[1],  p[2],  p[3]);
    base[256]  = make_float4(p[4],  p[5],  p[6],  p[7]);
    base[512]  = make_float4(iT[0], iT[1], iT[2], iT[3]);
    base[768]  = make_float4(iT[4], iT[5], iT[6], iT[7]);
    base[1024] = make_float4(k2[0], k2[1], k2[2], k2[3]);
    base[1280] = make_float4(k2[4], k2[5], k2[6], k2[7]);
}

// ---------------- fused convert (x, W) + PTK prep: one launch (big path) ----------------
__global__ __launch_bounds__(256) void cvt_prep(const float* __restrict__ x,
                                                const float* __restrict__ M,
                                                const float* __restrict__ Wres,
                                                const float* __restrict__ P,
                                                const float* __restrict__ periods,
                                                unsigned short* __restrict__ Xb,
                                                unsigned short* __restrict__ Wb,
                                                float4* __restrict__ PTK) {
    const int bid = blockIdx.x;
    if (bid >= 4224) {                       // PTK prep: 256 blocks
        prep_one(P, periods, PTK, (bid - 4224) * 256 + threadIdx.x);
        return;
    }
    const float* src;
    unsigned short* dst;
    if (bid < 4096) {
        const int idx = bid * 256 + threadIdx.x;
        src = x + (size_t)idx * 8;
        dst = Xb + (size_t)idx * 8;
    } else {
        const int idx = (bid - 4096) * 256 + threadIdx.x;
        const int row = idx >> 6;
        const int col = (idx & 63) * 8;
        src = (row < 256) ? (M + (size_t)row * 512 + col)
                          : (Wres + (size_t)(row - 256) * 512 + col);
        dst = Wb + (size_t)row * 512 + col;
    }
    const float4 v0 = *(const float4*)(src);
    const float4 v1 = *(const float4*)(src + 4);
    u16x8 o;
    o[0] = f2bf(v0.x); o[1] = f2bf(v0.y); o[2] = f2bf(v0.z); o[3] = f2bf(v0.w);
    o[4] = f2bf(v1.x); o[5] = f2bf(v1.y); o[6] = f2bf(v1.z); o[7] = f2bf(v1.w);
    *(u16x8*)dst = o;
}

// standalone versions for the aliased / fallback paths
__global__ __launch_bounds__(256) void cvt_xw(const float* __restrict__ x,
                                              const float* __restrict__ M,
                                              const float* __restrict__ Wres,
                                              unsigned short* __restrict__ Xb,
                                              unsigned short* __restrict__ Wb) {
    const int bid = blockIdx.x;
    const float* src;
    unsigned short* dst;
    if (bid < 4096) {
        const int idx = bid * 256 + threadIdx.x;
        src = x + (size_t)idx * 8;
        dst = Xb + (size_t)idx * 8;
    } else {
        const int idx = (bid - 4096) * 256 + threadIdx.x;
        const int row = idx >> 6;
        const int col = (idx & 63) * 8;
        src = (row < 256) ? (M + (size_t)row * 512 + col)
                          : (Wres + (size_t)(row - 256) * 512 + col);
        dst = Wb + (size_t)row * 512 + col;
    }
    const float4 v0 = *(const float4*)(src);
    const float4 v1 = *(const float4*)(src + 4);
    u16x8 o;
    o[0] = f2bf(v0.x); o[1] = f2bf(v0.y); o[2] = f2bf(v0.z); o[3] = f2bf(v0.w);
    o[4] = f2bf(v1.x); o[5] = f2bf(v1.y); o[6] = f2bf(v1.z); o[7] = f2bf(v1.w);
    *(u16x8*)dst = o;
}

__global__ __launch_bounds__(256) void prep_ptk(const float* __restrict__ P,
                                                const float* __restrict__ periods,
                                                float4* __restrict__ PTK) {
    prep_one(P, periods, PTK, blockIdx.x * 256 + threadIdx.x);
}

// ---------------- bf16 MFMA GEMM: C[16384,512] = Xb * Wb^T (unchanged, proven R5-R7) ----------------
__global__ __launch_bounds__(256) void gemm_mfma(const unsigned short* __restrict__ Xb,
                                                 const unsigned short* __restrict__ Wb,
                                                 float* __restrict__ y,
                                                 float* __restrict__ out) {
    __shared__ __align__(16) unsigned short At[64 * 64];    // 8 KB
    __shared__ __align__(16) unsigned short Bt[128 * 64];   // 16 KB
    const int t    = threadIdx.x;
    const int col0 = blockIdx.x * 128;
    const int row0 = blockIdx.y * 64;

    const unsigned short* ga[2]; int la[2];
    const unsigned short* gb[4]; int lb[4];
#pragma unroll
    for (int cc = 0; cc < 2; ++cc) {
        const int L = cc * 256 + t;
        const int r = L >> 3;
        const int c = (L & 7) ^ (r & 7);
        ga[cc] = Xb + (size_t)(row0 + r) * 512 + c * 8;
        la[cc] = L * 8;
    }
#pragma unroll
    for (int cc = 0; cc < 4; ++cc) {
        const int L = cc * 256 + t;
        const int r = L >> 3;
        const int c = (L & 7) ^ (r & 7);
        gb[cc] = Wb + (size_t)(col0 + r) * 512 + c * 8;
        lb[cc] = L * 8;
    }

    const int lane = t & 63;
    const int wave = t >> 6;
    const int wn   = wave * 32;
    const int quad = lane >> 4;
    const int l16  = lane & 15;

    f32x4 acc[4][2];
#pragma unroll
    for (int mi = 0; mi < 4; ++mi)
#pragma unroll
        for (int ni = 0; ni < 2; ++ni) acc[mi][ni] = {0.0f, 0.0f, 0.0f, 0.0f};

    for (int k0 = 0; k0 < 512; k0 += 64) {
        __syncthreads();
#pragma unroll
        for (int cc = 0; cc < 2; ++cc) gld16(ga[cc] + k0, At + la[cc]);
#pragma unroll
        for (int cc = 0; cc < 4; ++cc) gld16(gb[cc] + k0, Bt + lb[cc]);
        __syncthreads();
#pragma unroll
        for (int ks = 0; ks < 2; ++ks) {
            const int cc = (ks * 4 + quad) ^ (l16 & 7);
            s16x8 af[4], bf[2];
#pragma unroll
            for (int mi = 0; mi < 4; ++mi) {
                const int ra = mi * 16 + l16;
                af[mi] = *(const s16x8*)(At + (ra * 8 + cc) * 8);
            }
#pragma unroll
            for (int ni = 0; ni < 2; ++ni) {
                const int rb = wn + ni * 16 + l16;
                bf[ni] = *(const s16x8*)(Bt + (rb * 8 + cc) * 8);
            }
#pragma unroll
            for (int mi = 0; mi < 4; ++mi)
#pragma unroll
                for (int ni = 0; ni < 2; ++ni)
                    acc[mi][ni] = mfma_bf16(af[mi], bf[ni], acc[mi][ni]);
        }
    }

    float* dst   = (col0 < 256) ? y : out;
    const int cb = (col0 & 255) + wn;
#pragma unroll
    for (int mi = 0; mi < 4; ++mi) {
        const int rbase = row0 + mi * 16 + quad * 4;
#pragma unroll
        for (int ni = 0; ni < 2; ++ni) {
            const int col = cb + ni * 16 + l16;
#pragma unroll
            for (int rg = 0; rg < 4; ++rg)
                dst[(size_t)(rbase + rg) * 256 + col] = acc[mi][ni][rg];
        }
    }
}

// ---------------- fallback fp32 GEMM (proven) ----------------
__global__ __launch_bounds__(256) void gemm_kernel(const float* __restrict__ x,
                                                   const float* __restrict__ M,
                                                   const float* __restrict__ Wres,
                                                   float* __restrict__ y,
                                                   float* __restrict__ out) {
    __shared__ float As[8][132];
    __shared__ float Bs[8][132];
    const int ct = blockIdx.x;
    const int rt = blockIdx.y;
    const int t  = threadIdx.x;
    const int row0 = rt * 128;
    const float* W = (ct < 2) ? M : Wres;
    const int wcol0 = (ct & 1) * 128;
    float acc[8][8];
#pragma unroll
    for (int r = 0; r < 8; ++r)
#pragma unroll
        for (int c = 0; c < 8; ++c) acc[r][c] = 0.0f;
    const int lr = t >> 1;
    const int lk = (t & 1) << 2;
    for (int k0 = 0; k0 < 512; k0 += 8) {
        float4 av = *(const float4*)(x + (size_t)(row0 + lr) * 512 + k0 + lk);
        float4 bv = *(const float4*)(W + (size_t)(wcol0 + lr) * 512 + k0 + lk);
        __syncthreads();
        As[lk + 0][lr] = av.x; As[lk + 1][lr] = av.y; As[lk + 2][lr] = av.z; As[lk + 3][lr] = av.w;
        Bs[lk + 0][lr] = bv.x; Bs[lk + 1][lr] = bv.y; Bs[lk + 2][lr] = bv.z; Bs[lk + 3][lr] = bv.w;
        __syncthreads();
        const int tx = t & 15, ty = t >> 4;
#pragma unroll
        for (int kk = 0; kk < 8; ++kk) {
            const float4 a0 = *(const float4*)&As[kk][ty * 8];
            const float4 a1 = *(const float4*)&As[kk][ty * 8 + 4];
            const float4 b0 = *(const float4*)&Bs[kk][tx * 8];
            const float4 b1 = *(const float4*)&Bs[kk][tx * 8 + 4];
            const float ar[8] = {a0.x, a0.y, a0.z, a0.w, a1.x, a1.y, a1.z, a1.w};
            const float br[8] = {b0.x, b0.y, b0.z, b0.w, b1.x, b1.y, b1.z, b1.w};
#pragma unroll
            for (int r = 0; r < 8; ++r)
#pragma unroll
                for (int c = 0; c < 8; ++c) acc[r][c] = fmaf(ar[r], br[c], acc[r][c]);
        }
    }
    const int tx = t & 15, ty = t >> 4;
    float* dst = (ct < 2) ? y : out;
    const int cbase = (ct & 1) * 128 + tx * 8;
#pragma unroll
    for (int r = 0; r < 8; ++r) {
        float4 v0 = {acc[r][0], acc[r][1], acc[r][2], acc[r][3]};
        float4 v1 = {acc[r][4], acc[r][5], acc[r][6], acc[r][7]};
        float* p = dst + (size_t)(row0 + ty * 8 + r) * 256 + cbase;
        *(float4*)(p)     = v0;
        *(float4*)(p + 4) = v1;
    }
}

// ---------------- LayerNorm (in-place; mid/fallback paths) ----------------
__global__ __launch_bounds__(256) void ln_kernel(float* __restrict__ y,
                                                 const float* __restrict__ scale,
                                                 const float* __restrict__ bias) {
    const int t    = threadIdx.x;
    const int row  = blockIdx.x * 4 + (t >> 6);
    const int lane = t & 63;
    float* p = y + (size_t)row * 256 + lane * 4;
    float4 v = *(float4*)p;
    float s  = v.x + v.y + v.z + v.w;
    float ss = v.x * v.x + v.y * v.y + v.z * v.z + v.w * v.w;
#pragma unroll
    for (int off = 32; off > 0; off >>= 1) {
        s  += __shfl_xor(s, off);
        ss += __shfl_xor(ss, off);
    }
    const float mu  = s * (1.0f / 256.0f);
    const float var = ss * (1.0f / 256.0f) - mu * mu;
    const float rs  = rsqrtf(var + 1e-5f);
    float4 sc = *(const float4*)(scale + lane * 4);
    float4 bi = *(const float4*)(bias + lane * 4);
    float4 o;
    o.x = (v.x - mu) * rs * sc.x + bi.x;
    o.y = (v.y - mu) * rs * sc.y + bi.y;
    o.z = (v.z - mu) * rs * sc.z + bi.z;
    o.w = (v.w - mu) * rs * sc.w + bi.w;
    *(float4*)p = o;
}

// ---------------- R10: LayerNorm writing transposed xt2[stile][j][st][b] (big path) ----------------
// Element (b, s=stile*8+st, j) -> xt2[stile*16384 + j*64 + st*8 + b].
// Scattered 4B stores at 256B stride; full 64B lines are assembled in L2
// (each line = 16 consecutive (st,b) slots, all written within this dispatch).
__global__ __launch_bounds__(256) void ln_t(const float* __restrict__ y,
                                            const float* __restrict__ scale,
                                            const float* __restrict__ bias,
                                            float* __restrict__ xt2) {
    const int t    = threadIdx.x;
    const int row  = blockIdx.x * 4 + (t >> 6);       // b*2048 + s
    const int lane = t & 63;
    const float* p = y + (size_t)row * 256 + lane * 4;
    float4 v = *(const float4*)p;
    float s  = v.x + v.y + v.z + v.w;
    float ss = v.x * v.x + v.y * v.y + v.z * v.z + v.w * v.w;
#pragma unroll
    for (int off = 32; off > 0; off >>= 1) {
        s  += __shfl_xor(s, off);
        ss += __shfl_xor(ss, off);
    }
    const float mu  = s * (1.0f / 256.0f);
    const float var = ss * (1.0f / 256.0f) - mu * mu;
    const float rs  = rsqrtf(var + 1e-5f);
    float4 sc = *(const float4*)(scale + lane * 4);
    float4 bi = *(const float4*)(bias + lane * 4);
    float4 o;
    o.x = (v.x - mu) * rs * sc.x + bi.x;
    o.y = (v.y - mu) * rs * sc.y + bi.y;
    o.z = (v.z - mu) * rs * sc.z + bi.z;
    o.w = (v.w - mu) * rs * sc.w + bi.w;
    const int b = row >> 11;
    const int sidx = row & 2047;
    float* dst = xt2 + (size_t)(sidx >> 3) * 16384 + (size_t)lane * 256
                     + (sidx & 7) * 8 + b;
    dst[0]   = o.x;    // j = lane*4 + 0
    dst[64]  = o.y;    // j = lane*4 + 1
    dst[128] = o.z;    // j = lane*4 + 2
    dst[192] = o.w;    // j = lane*4 + 3
}

// ---------------- R8 cosnk (proven 124 us) — kept for mid/fallback paths ----------------
__global__ __launch_bounds__(256, 4) void cosnk_pk(const float4* __restrict__ PTK,
                                                   const float* __restrict__ xt,
                                                   float* __restrict__ out) {
    __shared__ float xs[128 * 64];   // [j_local][slot=s*8+b], 32 KB; reused for reduce
    const int t  = threadIdx.x;
    const int bx = blockIdx.x;
    const int ih = (bx >> 2) & 1;                  // XCD-pinned i-half
    const int rid = ((bx >> 3) << 2) | (bx & 3);   // 0..511
    const int stile = rid >> 1;                    // 0..255
    const int jh = rid & 1;
    const int s0 = stile * 8;
    const int jbase = jh * 128;

    {   // stage x_t[b][s0+st][jbase..+128] -> xs[j_local][slot]
        const int slot = t >> 2;        // 0..63 = st*8+b
        const int st   = slot >> 3;
        const int b    = slot & 7;
        const int jg   = t & 3;         // 32-j group
        const float* src = xt + (size_t)(b * S_ + s0 + st) * 256 + jbase + jg * 32;
#pragma unroll
        for (int q = 0; q < 8; ++q) {
            float4 v = *(const float4*)(src + 4 * q);
            const int jl = jg * 32 + 4 * q;
            xs[(jl + 0) * 64 + slot] = v.x;
            xs[(jl + 1) * 64 + slot] = v.y;
            xs[(jl + 2) * 64 + slot] = v.z;
            xs[(jl + 3) * 64 + slot] = v.w;
        }
    }
    __syncthreads();

    const int i   = ih * 128 + (t & 127);
    const int jq  = t >> 7;             // 0 or 1: 64-j quarter
    const int jl0 = jq * 64;
    const float sv0 = (float)s0;
    f32x2 sv0v; sv0v.x = sv0; sv0v.y = sv0;

    f32x2 accP[8][4];                   // [s][b-pair]
#pragma unroll
    for (int s = 0; s < 8; ++s)
#pragma unroll
        for (int q = 0; q < 4; ++q) { accP[s][q].x = 0.0f; accP[s][q].y = 0.0f; }

    const float4* ptk = PTK + (size_t)(jbase + jl0) * 1536 + i;
    float4 qp0 = ptk[0],    qp1 = ptk[256];   // p pairs
    float4 qt0 = ptk[512],  qt1 = ptk[768];   // iT pairs
    float4 qk0 = ptk[1024], qk1 = ptk[1280];  // 2cos(2pi iT) pairs

#define CHEBP(p2_, t2_, k2_)                                \
    do {                                                    \
        f32x2 f0 = sv0v * (t2_);                            \
        f0.x = fractf_(f0.x); f0.y = fractf_(f0.y);         \
        f32x2 c0; c0.x = cos2pi(f0.x); c0.y = cos2pi(f0.y); \
        f32x2 f1 = f0 + (t2_);                              \
        f1.x = fractf_(f1.x); f1.y = fractf_(f1.y);         \
        f32x2 c1; c1.x = cos2pi(f1.x); c1.y = cos2pi(f1.y); \
        f32x2 c2 = (k2_) * c1 - c0;                         \
        f32x2 c3 = (k2_) * c2 - c1;                         \
        f32x2 c4 = (k2_) * c3 - c2;                         \
        f32x2 c5 = (k2_) * c4 - c3;                         \
        f32x2 c6 = (k2_) * c5 - c4;                         \
        f32x2 c7 = (k2_) * c6 - c5;                         \
        A0 += (p2_) * c0; A1 += (p2_) * c1;                 \
        A2 += (p2_) * c2; A3 += (p2_) * c3;                 \
        A4 += (p2_) * c4; A5 += (p2_) * c5;                 \
        A6 += (p2_) * c6; A7 += (p2_) * c7;                 \
    } while (0)

    for (int jj = 0; jj < 64; ++jj) {
        const float4* pn = ptk + ((jj < 63) ? 1536 : 0);   // next-j prefetch
        const float4 n0 = pn[0],   n1 = pn[256],  n2 = pn[512];
        const float4 n3 = pn[768], n4 = pn[1024], n5 = pn[1280];

        f32x2 A0 = {0.f, 0.f}, A1 = {0.f, 0.f}, A2 = {0.f, 0.f}, A3 = {0.f, 0.f};
        f32x2 A4 = {0.f, 0.f}, A5 = {0.f, 0.f}, A6 = {0.f, 0.f}, A7 = {0.f, 0.f};
        CHEBP(lo2(qp0), lo2(qt0), lo2(qk0));   // g0,g1
        CHEBP(hi2(qp0), hi2(qt0), hi2(qk0));   // g2,g3
        CHEBP(lo2(qp1), lo2(qt1), lo2(qk1));   // g4,g5
        CHEBP(hi2(qp1), hi2(qt1), hi2(qk1));   // g6,g7

        const float as_[8] = {A0.x + A0.y, A1.x + A1.y, A2.x + A2.y, A3.x + A3.y,
                              A4.x + A4.y, A5.x + A5.y, A6.x + A6.y, A7.x + A7.y};

        const float* xrow = &xs[(jl0 + jj) * 64];   // wave-uniform -> LDS broadcast
#pragma unroll
        for (int s = 0; s < 8; ++s) {
            const float4 xa = *(const float4*)(xrow + s * 8);
            const float4 xb = *(const float4*)(xrow + s * 8 + 4);
            f32x2 av; av.x = as_[s]; av.y = as_[s];
            accP[s][0] += av * lo2(xa);
            accP[s][1] += av * hi2(xa);
            accP[s][2] += av * lo2(xb);
            accP[s][3] += av * hi2(xb);
        }
        qp0 = n0; qp1 = n1; qt0 = n2; qt1 = n3; qk0 = n4; qk1 = n5;
        ptk = pn;
    }

    // intra-block jq-reduce, then device-scope atomic add (2 blocks per element)
    __syncthreads();
    const int tl = t & 127;
    if (jq) {
#pragma unroll
        for (int slot = 0; slot < 64; ++slot) {
            const int st = slot >> 3, b = slot & 7;
            xs[slot * 128 + tl] = accP[st][b >> 1][b & 1];
        }
    }
    __syncthreads();
    if (!jq) {
#pragma unroll
        for (int slot = 0; slot < 64; ++slot) {
            const int st = slot >> 3, b = slot & 7;
            const float v = accP[st][b >> 1][b & 1] + xs[slot * 128 + tl];
            atomAddF(&out[(size_t)(b * S_ + s0 + st) * 256 + i], v);
        }
    }
}

// ---------------- R10: cosnk with scalar-broadcast x (big path) ----------------
// Identical geometry/registers to cosnk_pk; LDS staging + per-jj ds_reads replaced
// by wave-uniform global loads from xt2 (scalarized to s_load via readfirstlane-
// hoisted pointer). LDS used only for the tail jq-reduce.
__global__ __launch_bounds__(256, 4) void cosnk_sx(const float4* __restrict__ PTK,
                                                   const float* __restrict__ xt2,
                                                   float* __restrict__ out) {
    __shared__ float xs[64 * 128];   // tail-reduce only (32 KB)
    const int t  = threadIdx.x;
    const int bx = blockIdx.x;
    const int ih = (bx >> 2) & 1;                  // XCD-pinned i-half
    const int rid = ((bx >> 3) << 2) | (bx & 3);   // 0..511
    const int stile = rid >> 1;                    // 0..255
    const int jh = rid & 1;
    const int s0 = stile * 8;
    const int jbase = jh * 128;

    const int i   = ih * 128 + (t & 127);
    const int jq  = t >> 7;             // 0 or 1: 64-j quarter
    const int jl0 = jq * 64;
    const int jqu = __builtin_amdgcn_readfirstlane(jq);   // wave-uniform for scalar path
    const float* xcol = xt2 + (size_t)stile * 16384 + (size_t)(jbase + jqu * 64) * 64;

    const float sv0 = (float)s0;
    f32x2 sv0v; sv0v.x = sv0; sv0v.y = sv0;

    f32x2 accP[8][4];                   // [s][b-pair]
#pragma unroll
    for (int s = 0; s < 8; ++s)
#pragma unroll
        for (int q = 0; q < 4; ++q) { accP[s][q].x = 0.0f; accP[s][q].y = 0.0f; }

    const float4* ptk = PTK + (size_t)(jbase + jl0) * 1536 + i;
    float4 qp0 = ptk[0],    qp1 = ptk[256];   // p pairs
    float4 qt0 = ptk[512],  qt1 = ptk[768];   // iT pairs
    float4 qk0 = ptk[1024], qk1 = ptk[1280];  // 2cos(2pi iT) pairs

    for (int jj = 0; jj < 64; ++jj) {
        const float* xrow = xcol + jj * 64;                // uniform: 64 floats [st][b]
        const float4* pn = ptk + ((jj < 63) ? 1536 : 0);   // next-j prefetch
        const float4 n0 = pn[0],   n1 = pn[256],  n2 = pn[512];
        const float4 n3 = pn[768], n4 = pn[1024], n5 = pn[1280];

        f32x2 A0 = {0.f, 0.f}, A1 = {0.f, 0.f}, A2 = {0.f, 0.f}, A3 = {0.f, 0.f};
        f32x2 A4 = {0.f, 0.f}, A5 = {0.f, 0.f}, A6 = {0.f, 0.f}, A7 = {0.f, 0.f};
        CHEBP(lo2(qp0), lo2(qt0), lo2(qk0));   // g0,g1
        CHEBP(hi2(qp0), hi2(qt0), hi2(qk0));   // g2,g3
        CHEBP(lo2(qp1), lo2(qt1), lo2(qk1));   // g4,g5
        CHEBP(hi2(qp1), hi2(qt1), hi2(qk1));   // g6,g7

        const float as_[8] = {A0.x + A0.y, A1.x + A1.y, A2.x + A2.y, A3.x + A3.y,
                              A4.x + A4.y, A5.x + A5.y, A6.x + A6.y, A7.x + A7.y};

#pragma unroll
        for (int s = 0; s < 8; ++s) {
            const float4 xa = *(const float4*)(xrow + s * 8);       // s_load_dwordx4
            const float4 xb = *(const float4*)(xrow + s * 8 + 4);
            f32x2 av; av.x = as_[s]; av.y = as_[s];
            accP[s][0] += av * lo2(xa);
            accP[s][1] += av * hi2(xa);
            accP[s][2] += av * lo2(xb);
            accP[s][3] += av * hi2(xb);
        }
        qp0 = n0; qp1 = n1; qt0 = n2; qt1 = n3; qk0 = n4; qk1 = n5;
        ptk = pn;
    }
#undef CHEBP

    // intra-block jq-reduce, then device-scope atomic add (2 blocks per element)
    __syncthreads();
    const int tl = t & 127;
    if (jq) {
#pragma unroll
        for (int slot = 0; slot < 64; ++slot) {
            const int st = slot >> 3, b = slot & 7;
            xs[slot * 128 + tl] = accP[st][b >> 1][b & 1];
        }
    }
    __syncthreads();
    if (!jq) {
#pragma unroll
        for (int slot = 0; slot < 64; ++slot) {
            const int st = slot >> 3, b = slot & 7;
            const float v = accP[st][b >> 1][b & 1] + xs[slot * 128 + tl];
            atomAddF(&out[(size_t)(b * S_ + s0 + st) * 256 + i], v);
        }
    }
}

extern "C" void kernel_launch(void* const* d_in, const int* in_sizes, int n_in,
                              void* d_out, int out_size, void* d_ws, size_t ws_size,
                              hipStream_t stream) {
    const float* x        = (const float*)d_in[0];
    const float* M        = (const float*)d_in[1];
    const float* P        = (const float*)d_in[2];
    const float* Wres     = (const float*)d_in[3];
    const float* ln_scale = (const float*)d_in[4];
    const float* ln_bias  = (const float*)d_in[5];
    const float* periods  = (const float*)d_in[6];

    float* out = (float*)d_out;
    char*  wsb = (char*)d_ws;
    const size_t MB = 1024 * 1024;
    float* y = (float*)wsb;                                     // 16 MiB
    unsigned short* Xb = (unsigned short*)(wsb + 16 * MB);      // 16 MiB
    unsigned short* Wb = (unsigned short*)(wsb + 32 * MB);      // 0.5 MiB

    const bool big  = (ws_size >= 39 * MB);        // un-aliased PTK at 33 MiB
    const bool mfma = (ws_size >= (size_t)34078720);

    float4* PTK;
    if (big) {
        PTK = (float4*)(wsb + 33 * MB);
        float* xt2 = (float*)(wsb + 16 * MB);      // reuses Xb after gemm consumes it
        cvt_prep<<<4480, 256, 0, stream>>>(x, M, Wres, P, periods, Xb, Wb, PTK);
        dim3 ggrid(4, 256);
        gemm_mfma<<<ggrid, 256, 0, stream>>>(Xb, Wb, y, out);
        ln_t<<<4096, 256, 0, stream>>>(y, ln_scale, ln_bias, xt2);
        cosnk_sx<<<1024, 256, 0, stream>>>(PTK, xt2, out);
    } else if (mfma) {
        PTK = (float4*)(wsb + 16 * MB);            // aliases Xb; written after gemm
        cvt_xw<<<4224, 256, 0, stream>>>(x, M, Wres, Xb, Wb);
        dim3 ggrid(4, 256);
        gemm_mfma<<<ggrid, 256, 0, stream>>>(Xb, Wb, y, out);
        prep_ptk<<<256, 256, 0, stream>>>(P, periods, PTK);
        ln_kernel<<<4096, 256, 0, stream>>>(y, ln_scale, ln_bias);
        cosnk_pk<<<1024, 256, 0, stream>>>(PTK, y, out);
    } else {
        PTK = (float4*)(wsb + 16 * MB);
        dim3 ggrid(4, 128);
        gemm_kernel<<<ggrid, 256, 0, stream>>>(x, M, Wres, y, out);
        prep_ptk<<<256, 256, 0, stream>>>(P, periods, PTK);
        ln_kernel<<<4096, 256, 0, stream>>>(y, ln_scale, ln_bias);
        cosnk_pk<<<1024, 256, 0, stream>>>(PTK, y, out);
    }
}

// Round 7
// 233.094 us; speedup vs baseline: 5.1130x; 1.3151x over previous
//
#include <hip/hip_runtime.h>
#include <hip/hip_bf16.h>
#include <math.h>

#define B_   8
#define S_   2048
#define IN_  512
#define OUT_ 256
#define G_   8

// ws layout:
//  big path (ws >= 39 MiB):
//   [0,16MiB) y  [16,32MiB) Xb  [32,32.5) Wb  [33,39) PTK (un-aliased)
//  mid path (32.5 <= ws < 39 MiB): PTK aliases Xb at 16 MiB, written after gemm
//  fallback (ws < 32.5 MiB): fp32 gemm, y [0,16), PTK [16,22)
// PTK layout (R8): per j, 6 float4-quads x 256 i:
//   quad0 p[0..3] | quad1 p[4..7] | quad2 iT[0..3] | quad3 iT[4..7] | quad4 2cos(2pi iT)[0..3] | quad5 [4..7]
// R9 LESSON: cosnk true reg demand ~128; __launch_bounds__ min-waves > 4 -> spill disaster.
// R11 LESSON: LDS staging was NOT the bottleneck; scalar-broadcast x wash; ln_t stores -60us.
// R13/R14 LESSON: inline-asm v_pk_*_f32 (VOP3P packed fp32) MISCOMPILES on this toolchain —
//   R13 (neg mods) absmax 87, R14 (modifier-free, algebra verified on paper) absmax 207.
//   No builtin exists to force it; do NOT hand-write VOP3P f32. Reverted to R8 math.
// R15: R8 math restored verbatim; tail parallelized — jq-halves exchange HALF the slots
//   each (bit-identical sums, same atomics) -> serial tail chain 64 -> 32, all 256 threads active.

typedef float  f32x2  __attribute__((ext_vector_type(2)));
typedef float  f32x4  __attribute__((ext_vector_type(4)));
typedef short  s16x8  __attribute__((ext_vector_type(8)));
typedef __bf16 bf16x8 __attribute__((ext_vector_type(8)));
typedef unsigned short u16x8 __attribute__((ext_vector_type(8)));

__device__ __forceinline__ float cos2pi(float f) {
#if __has_builtin(__builtin_amdgcn_cosf)
    return __builtin_amdgcn_cosf(f);   // v_cos_f32: revolutions (verified R1-R7)
#else
    return __cosf(6.28318530717958647692f * f);
#endif
}

__device__ __forceinline__ float fractf_(float f) {
#if __has_builtin(__builtin_amdgcn_fractf)
    return __builtin_amdgcn_fractf(f);
#else
    return f - floorf(f);
#endif
}

__device__ __forceinline__ unsigned short f2bf(float f) {
    unsigned u = __builtin_bit_cast(unsigned, f);
    u += 0x7fffu + ((u >> 16) & 1u);   // RNE; inputs finite
    return (unsigned short)(u >> 16);
}

// hardware f32 atomic add when available; fallback atomicAdd
template <typename T>
__device__ __forceinline__ auto atomF_(T* p, T v, int) -> decltype(unsafeAtomicAdd(p, v)) {
    return unsafeAtomicAdd(p, v);
}
template <typename T>
__device__ __forceinline__ T atomF_(T* p, T v, long) {
    return atomicAdd(p, v);
}
__device__ __forceinline__ void atomAddF(float* p, float v) { atomF_(p, v, 0); }

// --- MFMA wrapper: tolerate either V8s(short) or V8y(__bf16) builtin signature ---
template <typename T>
__device__ __forceinline__ auto mfma_bf16_(T a, T b, f32x4 c, int)
    -> decltype(__builtin_amdgcn_mfma_f32_16x16x32_bf16(a, b, c, 0, 0, 0)) {
    return __builtin_amdgcn_mfma_f32_16x16x32_bf16(a, b, c, 0, 0, 0);
}
template <typename T>
__device__ __forceinline__ auto mfma_bf16_(T a, T b, f32x4 c, long)
    -> decltype(__builtin_amdgcn_mfma_f32_16x16x32_bf16(__builtin_bit_cast(bf16x8, a),
                                                        __builtin_bit_cast(bf16x8, b), c, 0, 0, 0)) {
    return __builtin_amdgcn_mfma_f32_16x16x32_bf16(__builtin_bit_cast(bf16x8, a),
                                                   __builtin_bit_cast(bf16x8, b), c, 0, 0, 0);
}
__device__ __forceinline__ f32x4 mfma_bf16(s16x8 a, s16x8 b, f32x4 c) {
    return mfma_bf16_(a, b, c, 0);
}

__device__ __forceinline__ void gld16(const void* g, void* l) {
    __builtin_amdgcn_global_load_lds((const __attribute__((address_space(1))) unsigned int*)g,
                                     (__attribute__((address_space(3))) unsigned int*)l,
                                     16, 0, 0);
}

__device__ __forceinline__ f32x2 lo2(float4 v) { f32x2 r; r.x = v.x; r.y = v.y; return r; }
__device__ __forceinline__ f32x2 hi2(float4 v) { f32x2 r; r.x = v.z; r.y = v.w; return r; }

// ---------------- device helper: prep one PTK record (pair-friendly layout) ----------------
__device__ __forceinline__ void prep_one(const float* __restrict__ P,
                                         const float* __restrict__ periods,
                                         float4* __restrict__ PTK, int tid) {
    const int j = tid >> 8, i = tid & 255;
    float p[8], iT[8], k2[8];
#pragma unroll
    for (int g = 0; g < 8; ++g) {
        const int idx = (i * 256 + j) * 8 + g;
        p[g]  = P[idx];
        iT[g] = 1.0f / periods[idx];
        k2[g] = 2.0f * cos2pi(iT[g]);
    }
    float4* base = PTK + (size_t)(j * 6) * 256 + i;
    base[0]    = make_float4(p[0],  p[1],  p[2],  p[3]);
    base[256]  = make_float4(p[4],  p[5],  p[6],  p[7]);
    base[512]  = make_float4(iT[0], iT[1], iT[2], iT[3]);
    base[768]  = make_float4(iT[4], iT[5], iT[6], iT[7]);
    base[1024] = make_float4(k2[0], k2[1], k2[2], k2[3]);
    base[1280] = make_float4(k2[4], k2[5], k2[6], k2[7]);
}

// ---------------- fused convert (x, W) + PTK prep: one launch (big path) ----------------
__global__ __launch_bounds__(256) void cvt_prep(const float* __restrict__ x,
                                                const float* __restrict__ M,
                                                const float* __restrict__ Wres,
                                                const float* __restrict__ P,
                                                const float* __restrict__ periods,
                                                unsigned short* __restrict__ Xb,
                                                unsigned short* __restrict__ Wb,
                                                float4* __restrict__ PTK) {
    const int bid = blockIdx.x;
    if (bid >= 4224) {                       // PTK prep: 256 blocks
        prep_one(P, periods, PTK, (bid - 4224) * 256 + threadIdx.x);
        return;
    }
    const float* src;
    unsigned short* dst;
    if (bid < 4096) {
        const int idx = bid * 256 + threadIdx.x;
        src = x + (size_t)idx * 8;
        dst = Xb + (size_t)idx * 8;
    } else {
        const int idx = (bid - 4096) * 256 + threadIdx.x;
        const int row = idx >> 6;
        const int col = (idx & 63) * 8;
        src = (row < 256) ? (M + (size_t)row * 512 + col)
                          : (Wres + (size_t)(row - 256) * 512 + col);
        dst = Wb + (size_t)row * 512 + col;
    }
    const float4 v0 = *(const float4*)(src);
    const float4 v1 = *(const float4*)(src + 4);
    u16x8 o;
    o[0] = f2bf(v0.x); o[1] = f2bf(v0.y); o[2] = f2bf(v0.z); o[3] = f2bf(v0.w);
    o[4] = f2bf(v1.x); o[5] = f2bf(v1.y); o[6] = f2bf(v1.z); o[7] = f2bf(v1.w);
    *(u16x8*)dst = o;
}

// standalone versions for the aliased / fallback paths
__global__ __launch_bounds__(256) void cvt_xw(const float* __restrict__ x,
                                              const float* __restrict__ M,
                                              const float* __restrict__ Wres,
                                              unsigned short* __restrict__ Xb,
                                              unsigned short* __restrict__ Wb) {
    const int bid = blockIdx.x;
    const float* src;
    unsigned short* dst;
    if (bid < 4096) {
        const int idx = bid * 256 + threadIdx.x;
        src = x + (size_t)idx * 8;
        dst = Xb + (size_t)idx * 8;
    } else {
        const int idx = (bid - 4096) * 256 + threadIdx.x;
        const int row = idx >> 6;
        const int col = (idx & 63) * 8;
        src = (row < 256) ? (M + (size_t)row * 512 + col)
                          : (Wres + (size_t)(row - 256) * 512 + col);
        dst = Wb + (size_t)row * 512 + col;
    }
    const float4 v0 = *(const float4*)(src);
    const float4 v1 = *(const float4*)(src + 4);
    u16x8 o;
    o[0] = f2bf(v0.x); o[1] = f2bf(v0.y); o[2] = f2bf(v0.z); o[3] = f2bf(v0.w);
    o[4] = f2bf(v1.x); o[5] = f2bf(v1.y); o[6] = f2bf(v1.z); o[7] = f2bf(v1.w);
    *(u16x8*)dst = o;
}

__global__ __launch_bounds__(256) void prep_ptk(const float* __restrict__ P,
                                                const float* __restrict__ periods,
                                                float4* __restrict__ PTK) {
    prep_one(P, periods, PTK, blockIdx.x * 256 + threadIdx.x);
}

// ---------------- bf16 MFMA GEMM: C[16384,512] = Xb * Wb^T (unchanged, proven R5-R7) ----------------
__global__ __launch_bounds__(256) void gemm_mfma(const unsigned short* __restrict__ Xb,
                                                 const unsigned short* __restrict__ Wb,
                                                 float* __restrict__ y,
                                                 float* __restrict__ out) {
    __shared__ __align__(16) unsigned short At[64 * 64];    // 8 KB
    __shared__ __align__(16) unsigned short Bt[128 * 64];   // 16 KB
    const int t    = threadIdx.x;
    const int col0 = blockIdx.x * 128;
    const int row0 = blockIdx.y * 64;

    const unsigned short* ga[2]; int la[2];
    const unsigned short* gb[4]; int lb[4];
#pragma unroll
    for (int cc = 0; cc < 2; ++cc) {
        const int L = cc * 256 + t;
        const int r = L >> 3;
        const int c = (L & 7) ^ (r & 7);
        ga[cc] = Xb + (size_t)(row0 + r) * 512 + c * 8;
        la[cc] = L * 8;
    }
#pragma unroll
    for (int cc = 0; cc < 4; ++cc) {
        const int L = cc * 256 + t;
        const int r = L >> 3;
        const int c = (L & 7) ^ (r & 7);
        gb[cc] = Wb + (size_t)(col0 + r) * 512 + c * 8;
        lb[cc] = L * 8;
    }

    const int lane = t & 63;
    const int wave = t >> 6;
    const int wn   = wave * 32;
    const int quad = lane >> 4;
    const int l16  = lane & 15;

    f32x4 acc[4][2];
#pragma unroll
    for (int mi = 0; mi < 4; ++mi)
#pragma unroll
        for (int ni = 0; ni < 2; ++ni) acc[mi][ni] = {0.0f, 0.0f, 0.0f, 0.0f};

    for (int k0 = 0; k0 < 512; k0 += 64) {
        __syncthreads();
#pragma unroll
        for (int cc = 0; cc < 2; ++cc) gld16(ga[cc] + k0, At + la[cc]);
#pragma unroll
        for (int cc = 0; cc < 4; ++cc) gld16(gb[cc] + k0, Bt + lb[cc]);
        __syncthreads();
#pragma unroll
        for (int ks = 0; ks < 2; ++ks) {
            const int cc = (ks * 4 + quad) ^ (l16 & 7);
            s16x8 af[4], bf[2];
#pragma unroll
            for (int mi = 0; mi < 4; ++mi) {
                const int ra = mi * 16 + l16;
                af[mi] = *(const s16x8*)(At + (ra * 8 + cc) * 8);
            }
#pragma unroll
            for (int ni = 0; ni < 2; ++ni) {
                const int rb = wn + ni * 16 + l16;
                bf[ni] = *(const s16x8*)(Bt + (rb * 8 + cc) * 8);
            }
#pragma unroll
            for (int mi = 0; mi < 4; ++mi)
#pragma unroll
                for (int ni = 0; ni < 2; ++ni)
                    acc[mi][ni] = mfma_bf16(af[mi], bf[ni], acc[mi][ni]);
        }
    }

    float* dst   = (col0 < 256) ? y : out;
    const int cb = (col0 & 255) + wn;
#pragma unroll
    for (int mi = 0; mi < 4; ++mi) {
        const int rbase = row0 + mi * 16 + quad * 4;
#pragma unroll
        for (int ni = 0; ni < 2; ++ni) {
            const int col = cb + ni * 16 + l16;
#pragma unroll
            for (int rg = 0; rg < 4; ++rg)
                dst[(size_t)(rbase + rg) * 256 + col] = acc[mi][ni][rg];
        }
    }
}

// ---------------- fallback fp32 GEMM (proven) ----------------
__global__ __launch_bounds__(256) void gemm_kernel(const float* __restrict__ x,
                                                   const float* __restrict__ M,
                                                   const float* __restrict__ Wres,
                                                   float* __restrict__ y,
                                                   float* __restrict__ out) {
    __shared__ float As[8][132];
    __shared__ float Bs[8][132];
    const int ct = blockIdx.x;
    const int rt = blockIdx.y;
    const int t  = threadIdx.x;
    const int row0 = rt * 128;
    const float* W = (ct < 2) ? M : Wres;
    const int wcol0 = (ct & 1) * 128;
    float acc[8][8];
#pragma unroll
    for (int r = 0; r < 8; ++r)
#pragma unroll
        for (int c = 0; c < 8; ++c) acc[r][c] = 0.0f;
    const int lr = t >> 1;
    const int lk = (t & 1) << 2;
    for (int k0 = 0; k0 < 512; k0 += 8) {
        float4 av = *(const float4*)(x + (size_t)(row0 + lr) * 512 + k0 + lk);
        float4 bv = *(const float4*)(W + (size_t)(wcol0 + lr) * 512 + k0 + lk);
        __syncthreads();
        As[lk + 0][lr] = av.x; As[lk + 1][lr] = av.y; As[lk + 2][lr] = av.z; As[lk + 3][lr] = av.w;
        Bs[lk + 0][lr] = bv.x; Bs[lk + 1][lr] = bv.y; Bs[lk + 2][lr] = bv.z; Bs[lk + 3][lr] = bv.w;
        __syncthreads();
        const int tx = t & 15, ty = t >> 4;
#pragma unroll
        for (int kk = 0; kk < 8; ++kk) {
            const float4 a0 = *(const float4*)&As[kk][ty * 8];
            const float4 a1 = *(const float4*)&As[kk][ty * 8 + 4];
            const float4 b0 = *(const float4*)&Bs[kk][tx * 8];
            const float4 b1 = *(const float4*)&Bs[kk][tx * 8 + 4];
            const float ar[8] = {a0.x, a0.y, a0.z, a0.w, a1.x, a1.y, a1.z, a1.w};
            const float br[8] = {b0.x, b0.y, b0.z, b0.w, b1.x, b1.y, b1.z, b1.w};
#pragma unroll
            for (int r = 0; r < 8; ++r)
#pragma unroll
                for (int c = 0; c < 8; ++c) acc[r][c] = fmaf(ar[r], br[c], acc[r][c]);
        }
    }
    const int tx = t & 15, ty = t >> 4;
    float* dst = (ct < 2) ? y : out;
    const int cbase = (ct & 1) * 128 + tx * 8;
#pragma unroll
    for (int r = 0; r < 8; ++r) {
        float4 v0 = {acc[r][0], acc[r][1], acc[r][2], acc[r][3]};
        float4 v1 = {acc[r][4], acc[r][5], acc[r][6], acc[r][7]};
        float* p = dst + (size_t)(row0 + ty * 8 + r) * 256 + cbase;
        *(float4*)(p)     = v0;
        *(float4*)(p + 4) = v1;
    }
}

// ---------------- LayerNorm (in-place; proven) ----------------
__global__ __launch_bounds__(256) void ln_kernel(float* __restrict__ y,
                                                 const float* __restrict__ scale,
                                                 const float* __restrict__ bias) {
    const int t    = threadIdx.x;
    const int row  = blockIdx.x * 4 + (t >> 6);
    const int lane = t & 63;
    float* p = y + (size_t)row * 256 + lane * 4;
    float4 v = *(float4*)p;
    float s  = v.x + v.y + v.z + v.w;
    float ss = v.x * v.x + v.y * v.y + v.z * v.z + v.w * v.w;
#pragma unroll
    for (int off = 32; off > 0; off >>= 1) {
        s  += __shfl_xor(s, off);
        ss += __shfl_xor(ss, off);
    }
    const float mu  = s * (1.0f / 256.0f);
    const float var = ss * (1.0f / 256.0f) - mu * mu;
    const float rs  = rsqrtf(var + 1e-5f);
    float4 sc = *(const float4*)(scale + lane * 4);
    float4 bi = *(const float4*)(bias + lane * 4);
    float4 o;
    o.x = (v.x - mu) * rs * sc.x + bi.x;
    o.y = (v.y - mu) * rs * sc.y + bi.y;
    o.z = (v.z - mu) * rs * sc.z + bi.z;
    o.w = (v.w - mu) * rs * sc.w + bi.w;
    *(float4*)p = o;
}

// ---------------- fused A-gen + contraction: R8 math (proven 124 us), R15 split tail ----------------
// grid 1024: block = 8 s x 128 i (i-half) x 128 j (j-half); threads 128 i x 2 jq.
// Chebyshev recurrences packed over g-pairs (f32x2); b-accumulation packed over b-pairs.
// cos/fract remain scalar (transcendental pipe).
__global__ __launch_bounds__(256, 4) void cosnk_pk(const float4* __restrict__ PTK,
                                                   const float* __restrict__ xt,
                                                   float* __restrict__ out) {
    __shared__ float xs[128 * 64];   // [j_local][slot=s*8+b], 32 KB; reused for reduce
    const int t  = threadIdx.x;
    const int bx = blockIdx.x;
    const int ih = (bx >> 2) & 1;                  // XCD-pinned i-half
    const int rid = ((bx >> 3) << 2) | (bx & 3);   // 0..511
    const int stile = rid >> 1;                    // 0..255
    const int jh = rid & 1;
    const int s0 = stile * 8;
    const int jbase = jh * 128;

    {   // stage x_t[b][s0+st][jbase..+128] -> xs[j_local][slot]
        const int slot = t >> 2;        // 0..63 = st*8+b
        const int st   = slot >> 3;
        const int b    = slot & 7;
        const int jg   = t & 3;         // 32-j group
        const float* src = xt + (size_t)(b * S_ + s0 + st) * 256 + jbase + jg * 32;
#pragma unroll
        for (int q = 0; q < 8; ++q) {
            float4 v = *(const float4*)(src + 4 * q);
            const int jl = jg * 32 + 4 * q;
            xs[(jl + 0) * 64 + slot] = v.x;
            xs[(jl + 1) * 64 + slot] = v.y;
            xs[(jl + 2) * 64 + slot] = v.z;
            xs[(jl + 3) * 64 + slot] = v.w;
        }
    }
    __syncthreads();

    const int i   = ih * 128 + (t & 127);
    const int jq  = t >> 7;             // 0 or 1: 64-j quarter
    const int jl0 = jq * 64;
    const float sv0 = (float)s0;
    f32x2 sv0v; sv0v.x = sv0; sv0v.y = sv0;

    f32x2 accP[8][4];                   // [s][b-pair]
#pragma unroll
    for (int s = 0; s < 8; ++s)
#pragma unroll
        for (int q = 0; q < 4; ++q) { accP[s][q].x = 0.0f; accP[s][q].y = 0.0f; }

    const float4* ptk = PTK + (size_t)(jbase + jl0) * 1536 + i;
    float4 qp0 = ptk[0],    qp1 = ptk[256];   // p pairs
    float4 qt0 = ptk[512],  qt1 = ptk[768];   // iT pairs
    float4 qk0 = ptk[1024], qk1 = ptk[1280];  // 2cos(2pi iT) pairs

#define CHEBP(p2_, t2_, k2_)                                \
    do {                                                    \
        f32x2 f0 = sv0v * (t2_);                            \
        f0.x = fractf_(f0.x); f0.y = fractf_(f0.y);         \
        f32x2 c0; c0.x = cos2pi(f0.x); c0.y = cos2pi(f0.y); \
        f32x2 f1 = f0 + (t2_);                              \
        f1.x = fractf_(f1.x); f1.y = fractf_(f1.y);         \
        f32x2 c1; c1.x = cos2pi(f1.x); c1.y = cos2pi(f1.y); \
        f32x2 c2 = (k2_) * c1 - c0;                         \
        f32x2 c3 = (k2_) * c2 - c1;                         \
        f32x2 c4 = (k2_) * c3 - c2;                         \
        f32x2 c5 = (k2_) * c4 - c3;                         \
        f32x2 c6 = (k2_) * c5 - c4;                         \
        f32x2 c7 = (k2_) * c6 - c5;                         \
        A0 += (p2_) * c0; A1 += (p2_) * c1;                 \
        A2 += (p2_) * c2; A3 += (p2_) * c3;                 \
        A4 += (p2_) * c4; A5 += (p2_) * c5;                 \
        A6 += (p2_) * c6; A7 += (p2_) * c7;                 \
    } while (0)

    for (int jj = 0; jj < 64; ++jj) {
        const float4* pn = ptk + ((jj < 63) ? 1536 : 0);   // next-j prefetch
        const float4 n0 = pn[0],   n1 = pn[256],  n2 = pn[512];
        const float4 n3 = pn[768], n4 = pn[1024], n5 = pn[1280];

        f32x2 A0 = {0.f, 0.f}, A1 = {0.f, 0.f}, A2 = {0.f, 0.f}, A3 = {0.f, 0.f};
        f32x2 A4 = {0.f, 0.f}, A5 = {0.f, 0.f}, A6 = {0.f, 0.f}, A7 = {0.f, 0.f};
        CHEBP(lo2(qp0), lo2(qt0), lo2(qk0));   // g0,g1
        CHEBP(hi2(qp0), hi2(qt0), hi2(qk0));   // g2,g3
        CHEBP(lo2(qp1), lo2(qt1), lo2(qk1));   // g4,g5
        CHEBP(hi2(qp1), hi2(qt1), hi2(qk1));   // g6,g7

        const float as_[8] = {A0.x + A0.y, A1.x + A1.y, A2.x + A2.y, A3.x + A3.y,
                              A4.x + A4.y, A5.x + A5.y, A6.x + A6.y, A7.x + A7.y};

        const float* xrow = &xs[(jl0 + jj) * 64];   // wave-uniform -> LDS broadcast
#pragma unroll
        for (int s = 0; s < 8; ++s) {
            const float4 xa = *(const float4*)(xrow + s * 8);
            const float4 xb = *(const float4*)(xrow + s * 8 + 4);
            f32x2 av; av.x = as_[s]; av.y = as_[s];
            accP[s][0] += av * lo2(xa);
            accP[s][1] += av * hi2(xa);
            accP[s][2] += av * lo2(xb);
            accP[s][3] += av * hi2(xb);
        }
        qp0 = n0; qp1 = n1; qt0 = n2; qt1 = n3; qk0 = n4; qk1 = n5;
        ptk = pn;
    }
#undef CHEBP

    // R15 tail: split slot exchange — jq1 hands slots 0..31 to jq0, jq0 hands 32..63
    // to jq1; each half combines + atomics its own 32. Bit-identical sums (commutative),
    // same atomic set; serial chain halved, all 256 threads active.
    const int tl = t & 127;
    __syncthreads();
    if (jq) {
#pragma unroll
        for (int slot = 0; slot < 32; ++slot) {
            const int st = slot >> 3, b = slot & 7;
            xs[slot * 128 + tl] = accP[st][b >> 1][b & 1];
        }
    } else {
#pragma unroll
        for (int slot = 32; slot < 64; ++slot) {
            const int st = slot >> 3, b = slot & 7;
            xs[4096 + (slot - 32) * 128 + tl] = accP[st][b >> 1][b & 1];
        }
    }
    __syncthreads();
    if (!jq) {
#pragma unroll
        for (int slot = 0; slot < 32; ++slot) {
            const int st = slot >> 3, b = slot & 7;
            const float v = accP[st][b >> 1][b & 1] + xs[slot * 128 + tl];
            atomAddF(&out[(size_t)(b * S_ + s0 + st) * 256 + i], v);
        }
    } else {
#pragma unroll
        for (int slot = 32; slot < 64; ++slot) {
            const int st = slot >> 3, b = slot & 7;
            const float v = accP[st][b >> 1][b & 1] + xs[4096 + (slot - 32) * 128 + tl];
            atomAddF(&out[(size_t)(b * S_ + s0 + st) * 256 + i], v);
        }
    }
}

extern "C" void kernel_launch(void* const* d_in, const int* in_sizes, int n_in,
                              void* d_out, int out_size, void* d_ws, size_t ws_size,
                              hipStream_t stream) {
    const float* x        = (const float*)d_in[0];
    const float* M        = (const float*)d_in[1];
    const float* P        = (const float*)d_in[2];
    const float* Wres     = (const float*)d_in[3];
    const float* ln_scale = (const float*)d_in[4];
    const float* ln_bias  = (const float*)d_in[5];
    const float* periods  = (const float*)d_in[6];

    float* out = (float*)d_out;
    char*  wsb = (char*)d_ws;
    const size_t MB = 1024 * 1024;
    float* y = (float*)wsb;                                     // 16 MiB
    unsigned short* Xb = (unsigned short*)(wsb + 16 * MB);      // 16 MiB
    unsigned short* Wb = (unsigned short*)(wsb + 32 * MB);      // 0.5 MiB

    const bool big  = (ws_size >= 39 * MB);        // un-aliased PTK at 33 MiB
    const bool mfma = (ws_size >= (size_t)34078720);

    float4* PTK;
    if (big) {
        PTK = (float4*)(wsb + 33 * MB);
        cvt_prep<<<4480, 256, 0, stream>>>(x, M, Wres, P, periods, Xb, Wb, PTK);
        dim3 ggrid(4, 256);
        gemm_mfma<<<ggrid, 256, 0, stream>>>(Xb, Wb, y, out);
    } else if (mfma) {
        PTK = (float4*)(wsb + 16 * MB);            // aliases Xb; written after gemm
        cvt_xw<<<4224, 256, 0, stream>>>(x, M, Wres, Xb, Wb);
        dim3 ggrid(4, 256);
        gemm_mfma<<<ggrid, 256, 0, stream>>>(Xb, Wb, y, out);
        prep_ptk<<<256, 256, 0, stream>>>(P, periods, PTK);
    } else {
        PTK = (float4*)(wsb + 16 * MB);
        dim3 ggrid(4, 128);
        gemm_kernel<<<ggrid, 256, 0, stream>>>(x, M, Wres, y, out);
        prep_ptk<<<256, 256, 0, stream>>>(P, periods, PTK);
    }

    ln_kernel<<<4096, 256, 0, stream>>>(y, ln_scale, ln_bias);

    cosnk_pk<<<1024, 256, 0, stream>>>(PTK, y, out);
}

// Round 11
// 232.715 us; speedup vs baseline: 5.1213x; 1.0016x over previous
//
#include <hip/hip_runtime.h>
#include <hip/hip_bf16.h>
#include <math.h>

#define B_   8
#define S_   2048
#define IN_  512
#define OUT_ 256
#define G_   8

// ws layout:
//  big path (ws >= 39 MiB):
//   [0,16MiB) y  [16,32MiB) Xb  [32,32.5) Wb  [33,39) PTK (un-aliased)
//  mid path (32.5 <= ws < 39 MiB): PTK aliases Xb at 16 MiB, written after gemm
//  fallback (ws < 32.5 MiB): fp32 gemm, y [0,16), PTK [16,22)
// PTK layout (R8): per j, 6 float4-quads x 256 i:
//   quad0 p[0..3] | quad1 p[4..7] | quad2 iT[0..3] | quad3 iT[4..7] | quad4 2cos(2pi iT)[0..3] | quad5 [4..7]
// R9 LESSON: cosnk true reg demand ~128; __launch_bounds__ min-waves > 4 -> spill disaster.
// R11 LESSON: LDS staging was NOT the bottleneck; scalar-broadcast x wash; ln_t scattered
//   stores cost ~64us (16MB at 256B-stride 4B stores) — inferred ln_kernel itself ~8us.
// R13/R14 LESSON: inline-asm v_pk_*_f32 (VOP3P packed fp32) MISCOMPILES on this toolchain —
//   absmax 87 / 207 on two variants (2nd modifier-free, algebra paper-verified). Dead path.
// R15: banked 233.1us — R8 math + split tail (serial chain 64->32), cosnk 121.7us.
// R16: non-cosnk mass ~111us; model says gemm_mfma ~60-75us (4 blocks/CU, vmcnt(0)-drain
//   per K-step, latency-bound). A-tile 64->32 rows, grid (4,512): 8 blocks/CU, 32 waves/CU.
// R17/R18/R19 = R16 resubmitted verbatim (R16-R18 benches were GPUAcquisitionTimeout; no data).

typedef float  f32x2  __attribute__((ext_vector_type(2)));
typedef float  f32x4  __attribute__((ext_vector_type(4)));
typedef short  s16x8  __attribute__((ext_vector_type(8)));
typedef __bf16 bf16x8 __attribute__((ext_vector_type(8)));
typedef unsigned short u16x8 __attribute__((ext_vector_type(8)));

__device__ __forceinline__ float cos2pi(float f) {
#if __has_builtin(__builtin_amdgcn_cosf)
    return __builtin_amdgcn_cosf(f);   // v_cos_f32: revolutions (verified R1-R7)
#else
    return __cosf(6.28318530717958647692f * f);
#endif
}

__device__ __forceinline__ float fractf_(float f) {
#if __has_builtin(__builtin_amdgcn_fractf)
    return __builtin_amdgcn_fractf(f);
#else
    return f - floorf(f);
#endif
}

__device__ __forceinline__ unsigned short f2bf(float f) {
    unsigned u = __builtin_bit_cast(unsigned, f);
    u += 0x7fffu + ((u >> 16) & 1u);   // RNE; inputs finite
    return (unsigned short)(u >> 16);
}

// hardware f32 atomic add when available; fallback atomicAdd
template <typename T>
__device__ __forceinline__ auto atomF_(T* p, T v, int) -> decltype(unsafeAtomicAdd(p, v)) {
    return unsafeAtomicAdd(p, v);
}
template <typename T>
__device__ __forceinline__ T atomF_(T* p, T v, long) {
    return atomicAdd(p, v);
}
__device__ __forceinline__ void atomAddF(float* p, float v) { atomF_(p, v, 0); }

// --- MFMA wrapper: tolerate either V8s(short) or V8y(__bf16) builtin signature ---
template <typename T>
__device__ __forceinline__ auto mfma_bf16_(T a, T b, f32x4 c, int)
    -> decltype(__builtin_amdgcn_mfma_f32_16x16x32_bf16(a, b, c, 0, 0, 0)) {
    return __builtin_amdgcn_mfma_f32_16x16x32_bf16(a, b, c, 0, 0, 0);
}
template <typename T>
__device__ __forceinline__ auto mfma_bf16_(T a, T b, f32x4 c, long)
    -> decltype(__builtin_amdgcn_mfma_f32_16x16x32_bf16(__builtin_bit_cast(bf16x8, a),
                                                        __builtin_bit_cast(bf16x8, b), c, 0, 0, 0)) {
    return __builtin_amdgcn_mfma_f32_16x16x32_bf16(__builtin_bit_cast(bf16x8, a),
                                                   __builtin_bit_cast(bf16x8, b), c, 0, 0, 0);
}
__device__ __forceinline__ f32x4 mfma_bf16(s16x8 a, s16x8 b, f32x4 c) {
    return mfma_bf16_(a, b, c, 0);
}

__device__ __forceinline__ void gld16(const void* g, void* l) {
    __builtin_amdgcn_global_load_lds((const __attribute__((address_space(1))) unsigned int*)g,
                                     (__attribute__((address_space(3))) unsigned int*)l,
                                     16, 0, 0);
}

__device__ __forceinline__ f32x2 lo2(float4 v) { f32x2 r; r.x = v.x; r.y = v.y; return r; }
__device__ __forceinline__ f32x2 hi2(float4 v) { f32x2 r; r.x = v.z; r.y = v.w; return r; }

// ---------------- device helper: prep one PTK record (pair-friendly layout) ----------------
__device__ __forceinline__ void prep_one(const float* __restrict__ P,
                                         const float* __restrict__ periods,
                                         float4* __restrict__ PTK, int tid) {
    const int j = tid >> 8, i = tid & 255;
    float p[8], iT[8], k2[8];
#pragma unroll
    for (int g = 0; g < 8; ++g) {
        const int idx = (i * 256 + j) * 8 + g;
        p[g]  = P[idx];
        iT[g] = 1.0f / periods[idx];
        k2[g] = 2.0f * cos2pi(iT[g]);
    }
    float4* base = PTK + (size_t)(j * 6) * 256 + i;
    base[0]    = make_float4(p[0],  p[1],  p[2],  p[3]);
    base[256]  = make_float4(p[4],  p[5],  p[6],  p[7]);
    base[512]  = make_float4(iT[0], iT[1], iT[2], iT[3]);
    base[768]  = make_float4(iT[4], iT[5], iT[6], iT[7]);
    base[1024] = make_float4(k2[0], k2[1], k2[2], k2[3]);
    base[1280] = make_float4(k2[4], k2[5], k2[6], k2[7]);
}

// ---------------- fused convert (x, W) + PTK prep: one launch (big path) ----------------
__global__ __launch_bounds__(256) void cvt_prep(const float* __restrict__ x,
                                                const float* __restrict__ M,
                                                const float* __restrict__ Wres,
                                                const float* __restrict__ P,
                                                const float* __restrict__ periods,
                                                unsigned short* __restrict__ Xb,
                                                unsigned short* __restrict__ Wb,
                                                float4* __restrict__ PTK) {
    const int bid = blockIdx.x;
    if (bid >= 4224) {                       // PTK prep: 256 blocks
        prep_one(P, periods, PTK, (bid - 4224) * 256 + threadIdx.x);
        return;
    }
    const float* src;
    unsigned short* dst;
    if (bid < 4096) {
        const int idx = bid * 256 + threadIdx.x;
        src = x + (size_t)idx * 8;
        dst = Xb + (size_t)idx * 8;
    } else {
        const int idx = (bid - 4096) * 256 + threadIdx.x;
        const int row = idx >> 6;
        const int col = (idx & 63) * 8;
        src = (row < 256) ? (M + (size_t)row * 512 + col)
                          : (Wres + (size_t)(row - 256) * 512 + col);
        dst = Wb + (size_t)row * 512 + col;
    }
    const float4 v0 = *(const float4*)(src);
    const float4 v1 = *(const float4*)(src + 4);
    u16x8 o;
    o[0] = f2bf(v0.x); o[1] = f2bf(v0.y); o[2] = f2bf(v0.z); o[3] = f2bf(v0.w);
    o[4] = f2bf(v1.x); o[5] = f2bf(v1.y); o[6] = f2bf(v1.z); o[7] = f2bf(v1.w);
    *(u16x8*)dst = o;
}

// standalone versions for the aliased / fallback paths
__global__ __launch_bounds__(256) void cvt_xw(const float* __restrict__ x,
                                              const float* __restrict__ M,
                                              const float* __restrict__ Wres,
                                              unsigned short* __restrict__ Xb,
                                              unsigned short* __restrict__ Wb) {
    const int bid = blockIdx.x;
    const float* src;
    unsigned short* dst;
    if (bid < 4096) {
        const int idx = bid * 256 + threadIdx.x;
        src = x + (size_t)idx * 8;
        dst = Xb + (size_t)idx * 8;
    } else {
        const int idx = (bid - 4096) * 256 + threadIdx.x;
        const int row = idx >> 6;
        const int col = (idx & 63) * 8;
        src = (row < 256) ? (M + (size_t)row * 512 + col)
                          : (Wres + (size_t)(row - 256) * 512 + col);
        dst = Wb + (size_t)row * 512 + col;
    }
    const float4 v0 = *(const float4*)(src);
    const float4 v1 = *(const float4*)(src + 4);
    u16x8 o;
    o[0] = f2bf(v0.x); o[1] = f2bf(v0.y); o[2] = f2bf(v0.z); o[3] = f2bf(v0.w);
    o[4] = f2bf(v1.x); o[5] = f2bf(v1.y); o[6] = f2bf(v1.z); o[7] = f2bf(v1.w);
    *(u16x8*)dst = o;
}

__global__ __launch_bounds__(256) void prep_ptk(const float* __restrict__ P,
                                                const float* __restrict__ periods,
                                                float4* __restrict__ PTK) {
    prep_one(P, periods, PTK, blockIdx.x * 256 + threadIdx.x);
}

// ---------------- bf16 MFMA GEMM: C[16384,512] = Xb * Wb^T ----------------
// R16: 32x128 tiles (was 64x128), grid (4,512) -> 8 blocks/CU, 32 waves/CU.
// Same staging swizzle; A-tile now one 256-thread chunk (cc loop gone).
__global__ __launch_bounds__(256) void gemm_mfma(const unsigned short* __restrict__ Xb,
                                                 const unsigned short* __restrict__ Wb,
                                                 float* __restrict__ y,
                                                 float* __restrict__ out) {
    __shared__ __align__(16) unsigned short At[32 * 64];    // 4 KB
    __shared__ __align__(16) unsigned short Bt[128 * 64];   // 16 KB
    const int t    = threadIdx.x;
    const int col0 = blockIdx.x * 128;
    const int row0 = blockIdx.y * 32;

    const unsigned short* ga;  int la;
    const unsigned short* gb[4]; int lb[4];
    {
        const int r = t >> 3;                 // 0..31
        const int c = (t & 7) ^ (r & 7);
        ga = Xb + (size_t)(row0 + r) * 512 + c * 8;
        la = t * 8;
    }
#pragma unroll
    for (int cc = 0; cc < 4; ++cc) {
        const int L = cc * 256 + t;
        const int r = L >> 3;
        const int c = (L & 7) ^ (r & 7);
        gb[cc] = Wb + (size_t)(col0 + r) * 512 + c * 8;
        lb[cc] = L * 8;
    }

    const int lane = t & 63;
    const int wave = t >> 6;
    const int wn   = wave * 32;
    const int quad = lane >> 4;
    const int l16  = lane & 15;

    f32x4 acc[2][2];
#pragma unroll
    for (int mi = 0; mi < 2; ++mi)
#pragma unroll
        for (int ni = 0; ni < 2; ++ni) acc[mi][ni] = {0.0f, 0.0f, 0.0f, 0.0f};

    for (int k0 = 0; k0 < 512; k0 += 64) {
        __syncthreads();
        gld16(ga + k0, At + la);
#pragma unroll
        for (int cc = 0; cc < 4; ++cc) gld16(gb[cc] + k0, Bt + lb[cc]);
        __syncthreads();
#pragma unroll
        for (int ks = 0; ks < 2; ++ks) {
            const int cc = (ks * 4 + quad) ^ (l16 & 7);
            s16x8 af[2], bf[2];
#pragma unroll
            for (int mi = 0; mi < 2; ++mi) {
                const int ra = mi * 16 + l16;
                af[mi] = *(const s16x8*)(At + (ra * 8 + cc) * 8);
            }
#pragma unroll
            for (int ni = 0; ni < 2; ++ni) {
                const int rb = wn + ni * 16 + l16;
                bf[ni] = *(const s16x8*)(Bt + (rb * 8 + cc) * 8);
            }
#pragma unroll
            for (int mi = 0; mi < 2; ++mi)
#pragma unroll
                for (int ni = 0; ni < 2; ++ni)
                    acc[mi][ni] = mfma_bf16(af[mi], bf[ni], acc[mi][ni]);
        }
    }

    float* dst   = (col0 < 256) ? y : out;
    const int cb = (col0 & 255) + wn;
#pragma unroll
    for (int mi = 0; mi < 2; ++mi) {
        const int rbase = row0 + mi * 16 + quad * 4;
#pragma unroll
        for (int ni = 0; ni < 2; ++ni) {
            const int col = cb + ni * 16 + l16;
#pragma unroll
            for (int rg = 0; rg < 4; ++rg)
                dst[(size_t)(rbase + rg) * 256 + col] = acc[mi][ni][rg];
        }
    }
}

// ---------------- fallback fp32 GEMM (proven) ----------------
__global__ __launch_bounds__(256) void gemm_kernel(const float* __restrict__ x,
                                                   const float* __restrict__ M,
                                                   const float* __restrict__ Wres,
                                                   float* __restrict__ y,
                                                   float* __restrict__ out) {
    __shared__ float As[8][132];
    __shared__ float Bs[8][132];
    const int ct = blockIdx.x;
    const int rt = blockIdx.y;
    const int t  = threadIdx.x;
    const int row0 = rt * 128;
    const float* W = (ct < 2) ? M : Wres;
    const int wcol0 = (ct & 1) * 128;
    float acc[8][8];
#pragma unroll
    for (int r = 0; r < 8; ++r)
#pragma unroll
        for (int c = 0; c < 8; ++c) acc[r][c] = 0.0f;
    const int lr = t >> 1;
    const int lk = (t & 1) << 2;
    for (int k0 = 0; k0 < 512; k0 += 8) {
        float4 av = *(const float4*)(x + (size_t)(row0 + lr) * 512 + k0 + lk);
        float4 bv = *(const float4*)(W + (size_t)(wcol0 + lr) * 512 + k0 + lk);
        __syncthreads();
        As[lk + 0][lr] = av.x; As[lk + 1][lr] = av.y; As[lk + 2][lr] = av.z; As[lk + 3][lr] = av.w;
        Bs[lk + 0][lr] = bv.x; Bs[lk + 1][lr] = bv.y; Bs[lk + 2][lr] = bv.z; Bs[lk + 3][lr] = bv.w;
        __syncthreads();
        const int tx = t & 15, ty = t >> 4;
#pragma unroll
        for (int kk = 0; kk < 8; ++kk) {
            const float4 a0 = *(const float4*)&As[kk][ty * 8];
            const float4 a1 = *(const float4*)&As[kk][ty * 8 + 4];
            const float4 b0 = *(const float4*)&Bs[kk][tx * 8];
            const float4 b1 = *(const float4*)&Bs[kk][tx * 8 + 4];
            const float ar[8] = {a0.x, a0.y, a0.z, a0.w, a1.x, a1.y, a1.z, a1.w};
            const float br[8] = {b0.x, b0.y, b0.z, b0.w, b1.x, b1.y, b1.z, b1.w};
#pragma unroll
            for (int r = 0; r < 8; ++r)
#pragma unroll
                for (int c = 0; c < 8; ++c) acc[r][c] = fmaf(ar[r], br[c], acc[r][c]);
        }
    }
    const int tx = t & 15, ty = t >> 4;
    float* dst = (ct < 2) ? y : out;
    const int cbase = (ct & 1) * 128 + tx * 8;
#pragma unroll
    for (int r = 0; r < 8; ++r) {
        float4 v0 = {acc[r][0], acc[r][1], acc[r][2], acc[r][3]};
        float4 v1 = {acc[r][4], acc[r][5], acc[r][6], acc[r][7]};
        float* p = dst + (size_t)(row0 + ty * 8 + r) * 256 + cbase;
        *(float4*)(p)     = v0;
        *(float4*)(p + 4) = v1;
    }
}

// ---------------- LayerNorm (in-place; proven) ----------------
__global__ __launch_bounds__(256) void ln_kernel(float* __restrict__ y,
                                                 const float* __restrict__ scale,
                                                 const float* __restrict__ bias) {
    const int t    = threadIdx.x;
    const int row  = blockIdx.x * 4 + (t >> 6);
    const int lane = t & 63;
    float* p = y + (size_t)row * 256 + lane * 4;
    float4 v = *(float4*)p;
    float s  = v.x + v.y + v.z + v.w;
    float ss = v.x * v.x + v.y * v.y + v.z * v.z + v.w * v.w;
#pragma unroll
    for (int off = 32; off > 0; off >>= 1) {
        s  += __shfl_xor(s, off);
        ss += __shfl_xor(ss, off);
    }
    const float mu  = s * (1.0f / 256.0f);
    const float var = ss * (1.0f / 256.0f) - mu * mu;
    const float rs  = rsqrtf(var + 1e-5f);
    float4 sc = *(const float4*)(scale + lane * 4);
    float4 bi = *(const float4*)(bias + lane * 4);
    float4 o;
    o.x = (v.x - mu) * rs * sc.x + bi.x;
    o.y = (v.y - mu) * rs * sc.y + bi.y;
    o.z = (v.z - mu) * rs * sc.z + bi.z;
    o.w = (v.w - mu) * rs * sc.w + bi.w;
    *(float4*)p = o;
}

// ---------------- fused A-gen + contraction: R8 math (proven 121.7 us), R15 split tail ----------------
// grid 1024: block = 8 s x 128 i (i-half) x 128 j (j-half); threads 128 i x 2 jq.
// Chebyshev recurrences packed over g-pairs (f32x2); b-accumulation packed over b-pairs.
// cos/fract remain scalar (transcendental pipe).
__global__ __launch_bounds__(256, 4) void cosnk_pk(const float4* __restrict__ PTK,
                                                   const float* __restrict__ xt,
                                                   float* __restrict__ out) {
    __shared__ float xs[128 * 64];   // [j_local][slot=s*8+b], 32 KB; reused for reduce
    const int t  = threadIdx.x;
    const int bx = blockIdx.x;
    const int ih = (bx >> 2) & 1;                  // XCD-pinned i-half
    const int rid = ((bx >> 3) << 2) | (bx & 3);   // 0..511
    const int stile = rid >> 1;                    // 0..255
    const int jh = rid & 1;
    const int s0 = stile * 8;
    const int jbase = jh * 128;

    {   // stage x_t[b][s0+st][jbase..+128] -> xs[j_local][slot]
        const int slot = t >> 2;        // 0..63 = st*8+b
        const int st   = slot >> 3;
        const int b    = slot & 7;
        const int jg   = t & 3;         // 32-j group
        const float* src = xt + (size_t)(b * S_ + s0 + st) * 256 + jbase + jg * 32;
#pragma unroll
        for (int q = 0; q < 8; ++q) {
            float4 v = *(const float4*)(src + 4 * q);
            const int jl = jg * 32 + 4 * q;
            xs[(jl + 0) * 64 + slot] = v.x;
            xs[(jl + 1) * 64 + slot] = v.y;
            xs[(jl + 2) * 64 + slot] = v.z;
            xs[(jl + 3) * 64 + slot] = v.w;
        }
    }
    __syncthreads();

    const int i   = ih * 128 + (t & 127);
    const int jq  = t >> 7;             // 0 or 1: 64-j quarter
    const int jl0 = jq * 64;
    const float sv0 = (float)s0;
    f32x2 sv0v; sv0v.x = sv0; sv0v.y = sv0;

    f32x2 accP[8][4];                   // [s][b-pair]
#pragma unroll
    for (int s = 0; s < 8; ++s)
#pragma unroll
        for (int q = 0; q < 4; ++q) { accP[s][q].x = 0.0f; accP[s][q].y = 0.0f; }

    const float4* ptk = PTK + (size_t)(jbase + jl0) * 1536 + i;
    float4 qp0 = ptk[0],    qp1 = ptk[256];   // p pairs
    float4 qt0 = ptk[512],  qt1 = ptk[768];   // iT pairs
    float4 qk0 = ptk[1024], qk1 = ptk[1280];  // 2cos(2pi iT) pairs

#define CHEBP(p2_, t2_, k2_)                                \
    do {                                                    \
        f32x2 f0 = sv0v * (t2_);                            \
        f0.x = fractf_(f0.x); f0.y = fractf_(f0.y);         \
        f32x2 c0; c0.x = cos2pi(f0.x); c0.y = cos2pi(f0.y); \
        f32x2 f1 = f0 + (t2_);                              \
        f1.x = fractf_(f1.x); f1.y = fractf_(f1.y);         \
        f32x2 c1; c1.x = cos2pi(f1.x); c1.y = cos2pi(f1.y); \
        f32x2 c2 = (k2_) * c1 - c0;                         \
        f32x2 c3 = (k2_) * c2 - c1;                         \
        f32x2 c4 = (k2_) * c3 - c2;                         \
        f32x2 c5 = (k2_) * c4 - c3;                         \
        f32x2 c6 = (k2_) * c5 - c4;                         \
        f32x2 c7 = (k2_) * c6 - c5;                         \
        A0 += (p2_) * c0; A1 += (p2_) * c1;                 \
        A2 += (p2_) * c2; A3 += (p2_) * c3;                 \
        A4 += (p2_) * c4; A5 += (p2_) * c5;                 \
        A6 += (p2_) * c6; A7 += (p2_) * c7;                 \
    } while (0)

    for (int jj = 0; jj < 64; ++jj) {
        const float4* pn = ptk + ((jj < 63) ? 1536 : 0);   // next-j prefetch
        const float4 n0 = pn[0],   n1 = pn[256],  n2 = pn[512];
        const float4 n3 = pn[768], n4 = pn[1024], n5 = pn[1280];

        f32x2 A0 = {0.f, 0.f}, A1 = {0.f, 0.f}, A2 = {0.f, 0.f}, A3 = {0.f, 0.f};
        f32x2 A4 = {0.f, 0.f}, A5 = {0.f, 0.f}, A6 = {0.f, 0.f}, A7 = {0.f, 0.f};
        CHEBP(lo2(qp0), lo2(qt0), lo2(qk0));   // g0,g1
        CHEBP(hi2(qp0), hi2(qt0), hi2(qk0));   // g2,g3
        CHEBP(lo2(qp1), lo2(qt1), lo2(qk1));   // g4,g5
        CHEBP(hi2(qp1), hi2(qt1), hi2(qk1));   // g6,g7

        const float as_[8] = {A0.x + A0.y, A1.x + A1.y, A2.x + A2.y, A3.x + A3.y,
                              A4.x + A4.y, A5.x + A5.y, A6.x + A6.y, A7.x + A7.y};

        const float* xrow = &xs[(jl0 + jj) * 64];   // wave-uniform -> LDS broadcast
#pragma unroll
        for (int s = 0; s < 8; ++s) {
            const float4 xa = *(const float4*)(xrow + s * 8);
            const float4 xb = *(const float4*)(xrow + s * 8 + 4);
            f32x2 av; av.x = as_[s]; av.y = as_[s];
            accP[s][0] += av * lo2(xa);
            accP[s][1] += av * hi2(xa);
            accP[s][2] += av * lo2(xb);
            accP[s][3] += av * hi2(xb);
        }
        qp0 = n0; qp1 = n1; qt0 = n2; qt1 = n3; qk0 = n4; qk1 = n5;
        ptk = pn;
    }
#undef CHEBP

    // R15 tail: split slot exchange — jq1 hands slots 0..31 to jq0, jq0 hands 32..63
    // to jq1; each half combines + atomics its own 32. Bit-identical sums (commutative),
    // same atomic set; serial chain halved, all 256 threads active.
    const int tl = t & 127;
    __syncthreads();
    if (jq) {
#pragma unroll
        for (int slot = 0; slot < 32; ++slot) {
            const int st = slot >> 3, b = slot & 7;
            xs[slot * 128 + tl] = accP[st][b >> 1][b & 1];
        }
    } else {
#pragma unroll
        for (int slot = 32; slot < 64; ++slot) {
            const int st = slot >> 3, b = slot & 7;
            xs[4096 + (slot - 32) * 128 + tl] = accP[st][b >> 1][b & 1];
        }
    }
    __syncthreads();
    if (!jq) {
#pragma unroll
        for (int slot = 0; slot < 32; ++slot) {
            const int st = slot >> 3, b = slot & 7;
            const float v = accP[st][b >> 1][b & 1] + xs[slot * 128 + tl];
            atomAddF(&out[(size_t)(b * S_ + s0 + st) * 256 + i], v);
        }
    } else {
#pragma unroll
        for (int slot = 32; slot < 64; ++slot) {
            const int st = slot >> 3, b = slot & 7;
            const float v = accP[st][b >> 1][b & 1] + xs[4096 + (slot - 32) * 128 + tl];
            atomAddF(&out[(size_t)(b * S_ + s0 + st) * 256 + i], v);
        }
    }
}

extern "C" void kernel_launch(void* const* d_in, const int* in_sizes, int n_in,
                              void* d_out, int out_size, void* d_ws, size_t ws_size,
                              hipStream_t stream) {
    const float* x        = (const float*)d_in[0];
    const float* M        = (const float*)d_in[1];
    const float* P        = (const float*)d_in[2];
    const float* Wres     = (const float*)d_in[3];
    const float* ln_scale = (const float*)d_in[4];
    const float* ln_bias  = (const float*)d_in[5];
    const float* periods  = (const float*)d_in[6];

    float* out = (float*)d_out;
    char*  wsb = (char*)d_ws;
    const size_t MB = 1024 * 1024;
    float* y = (float*)wsb;                                     // 16 MiB
    unsigned short* Xb = (unsigned short*)(wsb + 16 * MB);      // 16 MiB
    unsigned short* Wb = (unsigned short*)(wsb + 32 * MB);      // 0.5 MiB

    const bool big  = (ws_size >= 39 * MB);        // un-aliased PTK at 33 MiB
    const bool mfma = (ws_size >= (size_t)34078720);

    float4* PTK;
    if (big) {
        PTK = (float4*)(wsb + 33 * MB);
        cvt_prep<<<4480, 256, 0, stream>>>(x, M, Wres, P, periods, Xb, Wb, PTK);
        dim3 ggrid(4, 512);
        gemm_mfma<<<ggrid, 256, 0, stream>>>(Xb, Wb, y, out);
    } else if (mfma) {
        PTK = (float4*)(wsb + 16 * MB);            // aliases Xb; written after gemm
        cvt_xw<<<4224, 256, 0, stream>>>(x, M, Wres, Xb, Wb);
        dim3 ggrid(4, 512);
        gemm_mfma<<<ggrid, 256, 0, stream>>>(Xb, Wb, y, out);
        prep_ptk<<<256, 256, 0, stream>>>(P, periods, PTK);
    } else {
        PTK = (float4*)(wsb + 16 * MB);
        dim3 ggrid(4, 128);
        gemm_kernel<<<ggrid, 256, 0, stream>>>(x, M, Wres, y, out);
        prep_ptk<<<256, 256, 0, stream>>>(P, periods, PTK);
    }

    ln_kernel<<<4096, 256, 0, stream>>>(y, ln_scale, ln_bias);

    cosnk_pk<<<1024, 256, 0, stream>>>(PTK, y, out);
}